// Round 1
// 650.730 us; speedup vs baseline: 1.0412x; 1.0412x over previous
//
#include <hip/hip_runtime.h>
#include <math.h>

// Problem constants (from reference)
#define Nn 50000
#define MPAD 50048  // Nn padded to multiple of 128 (GEMM row tiles, no guards)
#define Ee 500000
#define Cc 256
#define Hh 128
#define Ll 4
#define Gg 64
#define Kk 8
#define NCc 2

#define NB 196  // ceil(Nn/256)

typedef __attribute__((ext_vector_type(8))) short short8;
typedef __attribute__((ext_vector_type(4))) float f32x4;

__device__ __forceinline__ unsigned short f2bf(float f) {
    union { float f; unsigned int u; } v;
    v.f = f;
    unsigned int u = v.u;
    return (unsigned short)((u + 0x7FFFu + ((u >> 16) & 1u)) >> 16);
}
__device__ __forceinline__ float bf2f(unsigned short s) {
    union { float f; unsigned int u; } v;
    v.u = ((unsigned int)s) << 16;
    return v.f;
}

// ---------------- CSR build ----------------

__global__ void hist_kernel(const int* __restrict__ dst, int* __restrict__ deg) {
    int e = blockIdx.x * 256 + threadIdx.x;
    if (e < Ee) atomicAdd(&deg[dst[e]], 1);
}

__global__ __launch_bounds__(256) void bsum_kernel(const int* __restrict__ deg,
                                                   int* __restrict__ bsum) {
    __shared__ int ws[4];
    int t = threadIdx.x;
    int i = blockIdx.x * 256 + t;
    int v = (i < Nn) ? deg[i] : 0;
#pragma unroll
    for (int o = 32; o; o >>= 1) v += __shfl_down(v, o, 64);
    if ((t & 63) == 0) ws[t >> 6] = v;
    __syncthreads();
    if (t == 0) bsum[blockIdx.x] = ws[0] + ws[1] + ws[2] + ws[3];
}

__global__ __launch_bounds__(256) void bscan_kernel(const int* __restrict__ bsum,
                                                    int* __restrict__ boff,
                                                    int* __restrict__ off) {
    __shared__ int sc[256];
    int t = threadIdx.x;
    int v = (t < NB) ? bsum[t] : 0;
    sc[t] = v;
    __syncthreads();
    for (int o = 1; o < 256; o <<= 1) {
        int u = (t >= o) ? sc[t - o] : 0;
        __syncthreads();
        sc[t] += u;
        __syncthreads();
    }
    if (t < NB) boff[t] = sc[t] - v;  // exclusive
    if (t == NB - 1) off[Nn] = sc[t];
}

__global__ __launch_bounds__(256) void offsets_kernel(const int* __restrict__ deg,
                                                      const int* __restrict__ boff,
                                                      int* __restrict__ off,
                                                      int* __restrict__ pos) {
    __shared__ int sc[256];
    int t = threadIdx.x;
    int i = blockIdx.x * 256 + t;
    int v = (i < Nn) ? deg[i] : 0;
    sc[t] = v;
    __syncthreads();
    for (int o = 1; o < 256; o <<= 1) {
        int u = (t >= o) ? sc[t - o] : 0;
        __syncthreads();
        sc[t] += u;
        __syncthreads();
    }
    int excl = sc[t] - v + boff[blockIdx.x];
    if (i < Nn) {
        off[i] = excl;
        pos[i] = excl;
    }
}

__global__ void scatter_kernel(const int* __restrict__ src, const int* __restrict__ dst,
                               const float* __restrict__ attr, int* __restrict__ pos,
                               int* __restrict__ ssrc, float* __restrict__ sattr) {
    int e = blockIdx.x * 256 + threadIdx.x;
    if (e < Ee) {
        int d = dst[e];
        int p = atomicAdd(&pos[d], 1);
        ssrc[p] = src[e];
        sattr[p] = attr[e];
    }
}

// ---------------- weight convert + transpose to bf16 [N][K] ----------------
// wt layout: [0, 65536)            proj  [256 n][256 k]  (n<128: lin_src col, else lin_dst)
//            [65536, 196608)       w1[l] [256 n][128 k]
//            [196608, 327680)      w2[l] [128 n][256 k]

__global__ void wconv_kernel(const float* __restrict__ lin_src_w,
                             const float* __restrict__ lin_dst_w,
                             const float* __restrict__ mlp_w1,
                             const float* __restrict__ mlp_w2,
                             unsigned short* __restrict__ wt) {
    int idx = blockIdx.x * 256 + threadIdx.x;
    if (idx >= 327680) return;
    float val;
    if (idx < 65536) {
        int n = idx >> 8, k = idx & 255;
        val = (n < 128) ? lin_src_w[k * 128 + n] : lin_dst_w[k * 128 + (n - 128)];
    } else if (idx < 196608) {
        int r = idx - 65536;
        int l = r >> 15, e = r & 32767;
        int n = e >> 7, k = e & 127;
        val = mlp_w1[(size_t)l * 32768 + k * 256 + n];
    } else {
        int r = idx - 196608;
        int l = r >> 15, e = r & 32767;
        int n = e >> 8, k = e & 255;
        val = mlp_w2[(size_t)l * 32768 + k * 128 + n];
    }
    wt[idx] = f2bf(val);
}

// ---------------- x fp32 -> bf16 (one-time, vectorized) ----------------

__global__ __launch_bounds__(256) void xconv_kernel(const float* __restrict__ x,
                                                    unsigned short* __restrict__ xbf) {
    int idx = blockIdx.x * 256 + threadIdx.x;  // 8 elems per thread
    if (idx >= (Nn * Cc) / 8) return;
    const float4* p = (const float4*)(x) + (size_t)idx * 2;
    float4 v0 = p[0], v1 = p[1];
    unsigned short t[8];
    t[0] = f2bf(v0.x); t[1] = f2bf(v0.y); t[2] = f2bf(v0.z); t[3] = f2bf(v0.w);
    t[4] = f2bf(v1.x); t[5] = f2bf(v1.y); t[6] = f2bf(v1.z); t[7] = f2bf(v1.w);
    *(short8*)(xbf + (size_t)idx * 8) = *(short8*)t;
}

// ---------------- bf16 MFMA GEMM (m97 structure: 128x128 tile, BK=32,
//                  4 waves, linear LDS, 16B global_load_lds staging) ----------------
// C[M,N] = A[M,K](bf16) @ B[N][K](bf16 transposed).  M padded to MPAD, no row guards.
// mode: 0 = bias (+bias2 for cols>=128), store bf16
//       1 = bias + BN + ReLU, store bf16
//       2 = bias + fp32 += CoutF; if pn_*: Rbuf = bf16(relu(BN_pn(new)))
//       3 = bias + fp32 store;   if pn_*: Rbuf = bf16(relu(BN_pn(new)))

#define BM 128
#define BN 128
#define BK 32

#define GLOAD16(gp, lp)                                                                       \
    __builtin_amdgcn_global_load_lds(                                                         \
        (const __attribute__((address_space(1))) unsigned int*)(gp),                          \
        (__attribute__((address_space(3))) unsigned int*)(lp), 16, 0, 0)

__global__ __launch_bounds__(256) void gemm_kernel(
    const unsigned short* __restrict__ A, const unsigned short* __restrict__ Bt,
    const float* __restrict__ bias, const float* __restrict__ bias2,
    const float* __restrict__ bn_g, const float* __restrict__ bn_b,
    const float* __restrict__ bn_m, const float* __restrict__ bn_v,
    const float* __restrict__ pn_g, const float* __restrict__ pn_b,
    const float* __restrict__ pn_m, const float* __restrict__ pn_v,
    float* __restrict__ CoutF, unsigned short* __restrict__ CoutB,
    unsigned short* __restrict__ Rbuf, int N, int K, int mode) {
    __shared__ __align__(16) unsigned short As[BM * BK];  // 8 KB, linear
    __shared__ __align__(16) unsigned short Bs[BN * BK];  // 8 KB, linear
    int tid = threadIdx.x;
    int wave = tid >> 6, lane = tid & 63;
    int wr = wave >> 1, wc = wave & 1;
    int lrow = lane & 15, quad = lane >> 4;
    int m0 = blockIdx.y * BM, n0 = blockIdx.x * BN;

    // staging: thread i of call c stages 16B at LDS byte (c*256+i)*16;
    // row = (c*256+i)>>2, col8 = (i&3)*8.  Sources must match that order exactly.
    const unsigned short* ag0 = A + (size_t)(m0 + (tid >> 2)) * K + (tid & 3) * 8;
    const unsigned short* ag1 = A + (size_t)(m0 + 64 + (tid >> 2)) * K + (tid & 3) * 8;
    const unsigned short* bg0 = Bt + (size_t)(n0 + (tid >> 2)) * K + (tid & 3) * 8;
    const unsigned short* bg1 = Bt + (size_t)(n0 + 64 + (tid >> 2)) * K + (tid & 3) * 8;
    unsigned short* lA0 = As + wave * 512;          // wave-uniform bases (HW adds lane*16B)
    unsigned short* lA1 = As + 2048 + wave * 512;
    unsigned short* lB0 = Bs + wave * 512;
    unsigned short* lB1 = Bs + 2048 + wave * 512;

    f32x4 acc[4][4];
#pragma unroll
    for (int i = 0; i < 4; i++)
#pragma unroll
        for (int j = 0; j < 4; j++) acc[i][j] = (f32x4){0.f, 0.f, 0.f, 0.f};

    for (int k0 = 0; k0 < K; k0 += BK) {
        __syncthreads();  // previous iteration's LDS reads done
        GLOAD16(ag0, lA0);
        GLOAD16(ag1, lA1);
        GLOAD16(bg0, lB0);
        GLOAD16(bg1, lB1);
        ag0 += BK; ag1 += BK; bg0 += BK; bg1 += BK;
        __syncthreads();  // staging landed (compiler drains vmcnt before barrier)
        short8 af[4], bf[4];
#pragma unroll
        for (int mt = 0; mt < 4; mt++)
            af[mt] = *(const short8*)&As[(wr * 64 + mt * 16 + lrow) * BK + quad * 8];
#pragma unroll
        for (int nt = 0; nt < 4; nt++)
            bf[nt] = *(const short8*)&Bs[(wc * 64 + nt * 16 + lrow) * BK + quad * 8];
#pragma unroll
        for (int mt = 0; mt < 4; mt++)
#pragma unroll
            for (int nt = 0; nt < 4; nt++)
                acc[mt][nt] = __builtin_amdgcn_mfma_f32_16x16x32_bf16(af[mt], bf[nt],
                                                                     acc[mt][nt], 0, 0, 0);
    }

#pragma unroll
    for (int nt = 0; nt < 4; nt++) {
        int gc = n0 + wc * 64 + nt * 16 + lrow;
        float bs = (bias2 && gc >= 128) ? bias2[gc - 128] : (bias ? bias[gc] : 0.f);
        float g = 1.f, bb = 0.f, mm = 0.f, inv = 1.f;
        if (mode == 1) {
            g = bn_g[gc];
            bb = bn_b[gc];
            mm = bn_m[gc];
            inv = rsqrtf(bn_v[gc] + 1e-5f);
        }
        float pg = 0.f, pb = 0.f, pm = 0.f, pinv = 0.f;
        if (mode >= 2 && pn_g) {
            pg = pn_g[gc];
            pb = pn_b[gc];
            pm = pn_m[gc];
            pinv = rsqrtf(pn_v[gc] + 1e-5f);
        }
#pragma unroll
        for (int mt = 0; mt < 4; mt++) {
#pragma unroll
            for (int r = 0; r < 4; r++) {
                int gr = m0 + wr * 64 + mt * 16 + quad * 4 + r;
                size_t idx = (size_t)gr * N + gc;
                float v = acc[mt][nt][r] + bs;
                if (mode == 0) {
                    CoutB[idx] = f2bf(v);
                } else if (mode == 1) {
                    v = fmaxf(g * (v - mm) * inv + bb, 0.f);
                    CoutB[idx] = f2bf(v);
                } else {
                    if (mode == 2) v += CoutF[idx];
                    CoutF[idx] = v;
                    if (pn_g)
                        Rbuf[idx] = f2bf(fmaxf(pg * (v - pm) * pinv + pb, 0.f));
                }
            }
        }
    }
}

// ---------------- Fused GENConv aggregation (one-pass online softmax) ----------------

__global__ __launch_bounds__(128) void agg_kernel(
    const unsigned short* __restrict__ xs, int xss,
    const unsigned short* __restrict__ xd, int xds,
    const int* __restrict__ ssrc, const float* __restrict__ sattr,
    const int* __restrict__ off,
    const float* __restrict__ ew, const float* __restrict__ eb,
    const float* __restrict__ tptr, unsigned short* __restrict__ outb) {
    int d = blockIdx.x;
    int hh = threadIdx.x;
    int s0 = off[d], s1 = off[d + 1];
    float w = ew[hh], b = eb[hh];
    float tl = tptr[0];
    float mmax = -INFINITY, denom = 0.f, num = 0.f;

#define EDGE_STEP(xv, av)                                  \
    {                                                      \
        float msg = fmaxf((xv) + (av)*w + b, 0.f) + 1e-7f; \
        float z = msg * tl;                                \
        float nm = fmaxf(mmax, z);                         \
        float c = __expf(mmax - nm);                       \
        float e = __expf(z - nm);                          \
        denom = denom * c + e;                             \
        num = num * c + msg * e;                           \
        mmax = nm;                                         \
    }

    int j = s0;
    for (; j + 3 < s1; j += 4) {
        int i0 = ssrc[j], i1 = ssrc[j + 1], i2 = ssrc[j + 2], i3 = ssrc[j + 3];
        float a0 = sattr[j], a1 = sattr[j + 1], a2 = sattr[j + 2], a3 = sattr[j + 3];
        float x0 = bf2f(xs[(size_t)i0 * xss + hh]);
        float x1 = bf2f(xs[(size_t)i1 * xss + hh]);
        float x2 = bf2f(xs[(size_t)i2 * xss + hh]);
        float x3 = bf2f(xs[(size_t)i3 * xss + hh]);
        EDGE_STEP(x0, a0)
        EDGE_STEP(x1, a1)
        EDGE_STEP(x2, a2)
        EDGE_STEP(x3, a3)
    }
    for (; j < s1; j++) {
        int s = ssrc[j];
        float a = sattr[j];
        float xv = bf2f(xs[(size_t)s * xss + hh]);
        EDGE_STEP(xv, a)
    }
    float agg = (s1 > s0) ? (num / fmaxf(denom, 1e-16f)) : 0.f;
    outb[(size_t)d * Hh + hh] = f2bf(agg + bf2f(xd[(size_t)d * xds + hh]));
#undef EDGE_STEP
}

// ---------------- final norm + hierarchical mean-pool ----------------

#define PCHUNK 100

__global__ __launch_bounds__(128) void pool_kernel(
    const float* __restrict__ h, const int* __restrict__ batch,
    const float* __restrict__ g, const float* __restrict__ b,
    const float* __restrict__ m, const float* __restrict__ v,
    float* __restrict__ pooled, float* __restrict__ cnt) {
    int hh = threadIdx.x;
    int i0 = blockIdx.x * PCHUNK;
    int i1 = min(i0 + PCHUNK, Nn);
    if (i0 >= Nn) return;
    float gg = g[hh], bb = b[hh], mm = m[hh], inv = rsqrtf(v[hh] + 1e-5f);
    int cur = batch[i0];
    float sum = 0.f, c = 0.f;
    for (int i = i0; i < i1; i++) {
        int gid = batch[i];
        float val = fmaxf(gg * (h[(size_t)i * Hh + hh] - mm) * inv + bb, 0.f);
        if (gid != cur) {
            atomicAdd(&pooled[(size_t)cur * Hh + hh], sum);
            if (hh == 0) atomicAdd(&cnt[cur], c);
            cur = gid;
            sum = 0.f;
            c = 0.f;
        }
        sum += val;
        c += 1.f;
    }
    atomicAdd(&pooled[(size_t)cur * Hh + hh], sum);
    if (hh == 0) atomicAdd(&cnt[cur], c);
}

// ---------------- classifier ----------------

__global__ __launch_bounds__(128) void cls_kernel(const float* __restrict__ pooled,
                                                  const float* __restrict__ cnt,
                                                  const float* __restrict__ clinical,
                                                  const float* __restrict__ w,
                                                  const float* __restrict__ bias,
                                                  float* __restrict__ out) {
    int t = threadIdx.x;
    int g = t >> 1, c = t & 1;
    float inv = 1.f / fmaxf(cnt[g], 1.f);
    float s = bias[c];
    for (int j = 0; j < Hh; j++) s += pooled[g * Hh + j] * inv * w[j * NCc + c];
    for (int k = 0; k < Kk; k++) s += clinical[g * Kk + k] * w[(Hh + k) * NCc + c];
    out[g * NCc + c] = s;
}

// ---------------- launch ----------------

extern "C" void kernel_launch(void* const* d_in, const int* in_sizes, int n_in,
                              void* d_out, int out_size, void* d_ws, size_t ws_size,
                              hipStream_t stream) {
    const float* x = (const float*)d_in[0];
    const int* eidx = (const int*)d_in[1];
    const float* eattr = (const float*)d_in[2];
    const int* batch = (const int*)d_in[3];
    const float* clinical = (const float*)d_in[4];
    const float* lin_src_w = (const float*)d_in[5];
    const float* lin_src_b = (const float*)d_in[6];
    const float* lin_dst_w = (const float*)d_in[7];
    const float* lin_dst_b = (const float*)d_in[8];
    const float* edge_w = (const float*)d_in[9];
    const float* edge_b = (const float*)d_in[10];
    const float* tt = (const float*)d_in[11];
    const float* mlp_w1 = (const float*)d_in[12];
    const float* mlp_b1 = (const float*)d_in[13];
    const float* bn_g = (const float*)d_in[14];
    const float* bn_b = (const float*)d_in[15];
    const float* bn_m = (const float*)d_in[16];
    const float* bn_v = (const float*)d_in[17];
    const float* mlp_w2 = (const float*)d_in[18];
    const float* mlp_b2 = (const float*)d_in[19];
    const float* norm_g = (const float*)d_in[20];
    const float* norm_b = (const float*)d_in[21];
    const float* norm_m = (const float*)d_in[22];
    const float* norm_v = (const float*)d_in[23];
    const float* cls_w = (const float*)d_in[24];
    const float* cls_b = (const float*)d_in[25];
    float* out = (float*)d_out;

    const int* src = eidx;
    const int* dst = eidx + Ee;

    char* ws = (char*)d_ws;
    size_t off_b = 0;
    auto alloc = [&](size_t bytes) -> void* {
        void* p = ws + off_b;
        off_b += (bytes + 255) & ~(size_t)255;
        return p;
    };
    // All GEMM-touched buffers padded to MPAD rows (garbage pad rows never read).
    unsigned short* xsd = (unsigned short*)alloc((size_t)MPAD * 256 * 2);   // proj out
    unsigned short* rbuf = (unsigned short*)alloc((size_t)MPAD * Hh * 2);   // prenorm out
    unsigned short* aggout = (unsigned short*)alloc((size_t)MPAD * Hh * 2);
    unsigned short* hmid = (unsigned short*)alloc((size_t)MPAD * 2 * Hh * 2);
    float* hbuf = (float*)alloc((size_t)MPAD * Hh * 4);
    int* deg = (int*)alloc((Nn + 1) * 4);
    int* offp = (int*)alloc((Nn + 1) * 4);
    int* pos = (int*)alloc((size_t)Nn * 4);
    int* bsum = (int*)alloc(NB * 4);
    int* boff = (int*)alloc(NB * 4);
    int* ssrc = (int*)alloc((size_t)Ee * 4);
    float* sattr = (float*)alloc((size_t)Ee * 4);
    float* pooled = (float*)alloc((size_t)Gg * Hh * 4);
    float* cntb = (float*)alloc(Gg * 4);
    unsigned short* wt = (unsigned short*)alloc((size_t)327680 * 2);
    // xbf aliases hmid: proj (reads xbf) completes before w1 writes hmid.
    unsigned short* xbf = hmid;

    hipMemsetAsync(deg, 0, (Nn + 1) * 4, stream);
    hipMemsetAsync(pooled, 0, (size_t)Gg * Hh * 4, stream);
    hipMemsetAsync(cntb, 0, Gg * 4, stream);

    hist_kernel<<<(Ee + 255) / 256, 256, 0, stream>>>(dst, deg);
    bsum_kernel<<<NB, 256, 0, stream>>>(deg, bsum);
    bscan_kernel<<<1, 256, 0, stream>>>(bsum, boff, offp);
    offsets_kernel<<<NB, 256, 0, stream>>>(deg, boff, offp, pos);
    scatter_kernel<<<(Ee + 255) / 256, 256, 0, stream>>>(src, dst, eattr, pos, ssrc, sattr);
    wconv_kernel<<<1280, 256, 0, stream>>>(lin_src_w, lin_dst_w, mlp_w1, mlp_w2, wt);
    xconv_kernel<<<(Nn * Cc / 8 + 255) / 256, 256, 0, stream>>>(x, xbf);

    const unsigned short* wt_proj = wt;
    const unsigned short* wt_w1 = wt + 65536;
    const unsigned short* wt_w2 = wt + 196608;

    // Fused projection: xsd[:, :128] = x@Wsrc+b, xsd[:, 128:] = x@Wdst+b
    dim3 gproj(256 / BN, MPAD / BM);
    gemm_kernel<<<gproj, 256, 0, stream>>>(xbf, wt_proj, lin_src_b, lin_dst_b,
                                           nullptr, nullptr, nullptr, nullptr,
                                           nullptr, nullptr, nullptr, nullptr,
                                           nullptr, xsd, nullptr, 256, Cc, 0);

    for (int l = 0; l < Ll; l++) {
        const unsigned short* cxs;
        const unsigned short* cxd;
        int xss, xds;
        if (l == 0) {
            cxs = xsd;
            xss = 256;
            cxd = xsd + 128;
            xds = 256;
        } else {
            // rbuf was produced by previous layer's w2 epilogue (fused prenorm)
            cxs = rbuf;
            xss = Hh;
            cxd = rbuf;
            xds = Hh;
        }
        agg_kernel<<<Nn, 128, 0, stream>>>(cxs, xss, cxd, xds, ssrc, sattr, offp,
                                           edge_w + l * Hh, edge_b + l * Hh, tt + l, aggout);
        dim3 g1((2 * Hh) / BN, MPAD / BM);
        gemm_kernel<<<g1, 256, 0, stream>>>(aggout, wt_w1 + (size_t)l * 32768,
                                            mlp_b1 + l * 2 * Hh, nullptr,
                                            bn_g + l * 2 * Hh, bn_b + l * 2 * Hh,
                                            bn_m + l * 2 * Hh, bn_v + l * 2 * Hh,
                                            nullptr, nullptr, nullptr, nullptr,
                                            nullptr, hmid, nullptr, 2 * Hh, Hh, 1);
        // w2 epilogue: residual += (mode 2) / store (mode 3, l==0) into hbuf,
        // plus fused prenorm for next layer into rbuf (norm params l+1).
        const float* png = (l < Ll - 1) ? (norm_g + (l + 1) * Hh) : nullptr;
        const float* pnb = (l < Ll - 1) ? (norm_b + (l + 1) * Hh) : nullptr;
        const float* pnm = (l < Ll - 1) ? (norm_m + (l + 1) * Hh) : nullptr;
        const float* pnv = (l < Ll - 1) ? (norm_v + (l + 1) * Hh) : nullptr;
        dim3 g2(Hh / BN, MPAD / BM);
        gemm_kernel<<<g2, 256, 0, stream>>>(hmid, wt_w2 + (size_t)l * 32768,
                                            mlp_b2 + l * Hh, nullptr,
                                            nullptr, nullptr, nullptr, nullptr,
                                            png, pnb, pnm, pnv,
                                            hbuf, nullptr, rbuf, Hh, 2 * Hh,
                                            (l == 0) ? 3 : 2);
    }

    pool_kernel<<<(Nn + PCHUNK - 1) / PCHUNK, 128, 0, stream>>>(hbuf, batch, norm_g, norm_b,
                                                                norm_m, norm_v, pooled, cntb);
    cls_kernel<<<1, 128, 0, stream>>>(pooled, cntb, clinical, cls_w, cls_b, out);
}

// Round 2
// 630.322 us; speedup vs baseline: 1.0749x; 1.0324x over previous
//
#include <hip/hip_runtime.h>
#include <math.h>

// Problem constants (from reference)
#define Nn 50000
#define MPAD 50048  // Nn padded to multiple of 128 (GEMM row tiles, no guards)
#define Ee 500000
#define Cc 256
#define Hh 128
#define Ll 4
#define Gg 64
#define Kk 8
#define NCc 2

#define NB 196  // ceil(Nn/256)

typedef __attribute__((ext_vector_type(8))) short short8;
typedef __attribute__((ext_vector_type(4))) float f32x4;

__device__ __forceinline__ unsigned short f2bf(float f) {
    union { float f; unsigned int u; } v;
    v.f = f;
    unsigned int u = v.u;
    return (unsigned short)((u + 0x7FFFu + ((u >> 16) & 1u)) >> 16);
}
__device__ __forceinline__ float bf2f(unsigned short s) {
    union { float f; unsigned int u; } v;
    v.u = ((unsigned int)s) << 16;
    return v.f;
}

// ---------------- CSR build ----------------

__global__ void hist_kernel(const int* __restrict__ dst, int* __restrict__ deg) {
    int e = blockIdx.x * 256 + threadIdx.x;
    if (e < Ee) atomicAdd(&deg[dst[e]], 1);
}

__global__ __launch_bounds__(256) void bsum_kernel(const int* __restrict__ deg,
                                                   int* __restrict__ bsum) {
    __shared__ int ws[4];
    int t = threadIdx.x;
    int i = blockIdx.x * 256 + t;
    int v = (i < Nn) ? deg[i] : 0;
#pragma unroll
    for (int o = 32; o; o >>= 1) v += __shfl_down(v, o, 64);
    if ((t & 63) == 0) ws[t >> 6] = v;
    __syncthreads();
    if (t == 0) bsum[blockIdx.x] = ws[0] + ws[1] + ws[2] + ws[3];
}

__global__ __launch_bounds__(256) void bscan_kernel(const int* __restrict__ bsum,
                                                    int* __restrict__ boff,
                                                    int* __restrict__ off) {
    __shared__ int sc[256];
    int t = threadIdx.x;
    int v = (t < NB) ? bsum[t] : 0;
    sc[t] = v;
    __syncthreads();
    for (int o = 1; o < 256; o <<= 1) {
        int u = (t >= o) ? sc[t - o] : 0;
        __syncthreads();
        sc[t] += u;
        __syncthreads();
    }
    if (t < NB) boff[t] = sc[t] - v;  // exclusive
    if (t == NB - 1) off[Nn] = sc[t];
}

__global__ __launch_bounds__(256) void offsets_kernel(const int* __restrict__ deg,
                                                      const int* __restrict__ boff,
                                                      int* __restrict__ off,
                                                      int* __restrict__ pos) {
    __shared__ int sc[256];
    int t = threadIdx.x;
    int i = blockIdx.x * 256 + t;
    int v = (i < Nn) ? deg[i] : 0;
    sc[t] = v;
    __syncthreads();
    for (int o = 1; o < 256; o <<= 1) {
        int u = (t >= o) ? sc[t - o] : 0;
        __syncthreads();
        sc[t] += u;
        __syncthreads();
    }
    int excl = sc[t] - v + boff[blockIdx.x];
    if (i < Nn) {
        off[i] = excl;
        pos[i] = excl;
    }
}

__global__ void scatter_kernel(const int* __restrict__ src, const int* __restrict__ dst,
                               const float* __restrict__ attr, int* __restrict__ pos,
                               int* __restrict__ ssrc, float* __restrict__ sattr) {
    int e = blockIdx.x * 256 + threadIdx.x;
    if (e < Ee) {
        int d = dst[e];
        int p = atomicAdd(&pos[d], 1);
        ssrc[p] = src[e];
        sattr[p] = attr[e];
    }
}

// ---------------- weight convert + transpose to bf16 [N][K] ----------------
// wt layout: [0, 65536)            proj  [256 n][256 k]  (n<128: lin_src col, else lin_dst)
//            [65536, 196608)       w1[l] [256 n][128 k]
//            [196608, 327680)      w2[l] [128 n][256 k]

__global__ void wconv_kernel(const float* __restrict__ lin_src_w,
                             const float* __restrict__ lin_dst_w,
                             const float* __restrict__ mlp_w1,
                             const float* __restrict__ mlp_w2,
                             unsigned short* __restrict__ wt) {
    int idx = blockIdx.x * 256 + threadIdx.x;
    if (idx >= 327680) return;
    float val;
    if (idx < 65536) {
        int n = idx >> 8, k = idx & 255;
        val = (n < 128) ? lin_src_w[k * 128 + n] : lin_dst_w[k * 128 + (n - 128)];
    } else if (idx < 196608) {
        int r = idx - 65536;
        int l = r >> 15, e = r & 32767;
        int n = e >> 7, k = e & 127;
        val = mlp_w1[(size_t)l * 32768 + k * 256 + n];
    } else {
        int r = idx - 196608;
        int l = r >> 15, e = r & 32767;
        int n = e >> 8, k = e & 255;
        val = mlp_w2[(size_t)l * 32768 + k * 128 + n];
    }
    wt[idx] = f2bf(val);
}

// ---------------- x fp32 -> bf16 (one-time, vectorized) ----------------

__global__ __launch_bounds__(256) void xconv_kernel(const float* __restrict__ x,
                                                    unsigned short* __restrict__ xbf) {
    int idx = blockIdx.x * 256 + threadIdx.x;  // 8 elems per thread
    if (idx >= (Nn * Cc) / 8) return;
    const float4* p = (const float4*)(x) + (size_t)idx * 2;
    float4 v0 = p[0], v1 = p[1];
    unsigned short t[8];
    t[0] = f2bf(v0.x); t[1] = f2bf(v0.y); t[2] = f2bf(v0.z); t[3] = f2bf(v0.w);
    t[4] = f2bf(v1.x); t[5] = f2bf(v1.y); t[6] = f2bf(v1.z); t[7] = f2bf(v1.w);
    *(short8*)(xbf + (size_t)idx * 8) = *(short8*)t;
}

// ---------------- bf16 MFMA GEMM: 128xBNt tile, BK=32, 4 waves,
//                  double-buffered LDS, 2-phase prefetch pipeline (T3-min) ----------------
// C[M,N] = A[M,K](bf16) @ B[N][K](bf16 transposed).  M padded to MPAD, no row guards.
// mode: 0 = bias (+bias2 for cols>=128), store bf16
//       1 = bias + BN + ReLU, store bf16
//       2 = bias + fp32 += CoutF; if pn_*: Rbuf = bf16(relu(BN_pn(new)))
//       3 = bias + fp32 store;   if pn_*: Rbuf = bf16(relu(BN_pn(new)))

#define BM 128
#define BK 32

#define GLOAD16(gp, lp)                                                                       \
    __builtin_amdgcn_global_load_lds(                                                         \
        (const __attribute__((address_space(1))) unsigned int*)(gp),                          \
        (__attribute__((address_space(3))) unsigned int*)(lp), 16, 0, 0)

template <int BNt>
__global__ __launch_bounds__(256) void gemm_kernel(
    const unsigned short* __restrict__ A, const unsigned short* __restrict__ Bt,
    const float* __restrict__ bias, const float* __restrict__ bias2,
    const float* __restrict__ bn_g, const float* __restrict__ bn_b,
    const float* __restrict__ bn_m, const float* __restrict__ bn_v,
    const float* __restrict__ pn_g, const float* __restrict__ pn_b,
    const float* __restrict__ pn_m, const float* __restrict__ pn_v,
    float* __restrict__ CoutF, unsigned short* __restrict__ CoutB,
    unsigned short* __restrict__ Rbuf, int N, int K, int mode) {
    constexpr int WC = BNt / 64;        // wave grid cols (1 or 2)
    constexpr int WR = 4 / WC;          // wave grid rows (4 or 2)
    constexpr int MT = BM / (WR * 16);  // 16-row frags per wave (2 or 4)
    constexpr int BCH = (BNt * BK) / 2048;  // 4KB staging chunks for B (1 or 2)

    __shared__ __align__(16) unsigned short As[2][BM * BK];   // 2 x 8 KB
    __shared__ __align__(16) unsigned short Bs[2][BNt * BK];  // 2 x (4|8) KB

    int tid = threadIdx.x;
    int wave = tid >> 6, lane = tid & 63;
    int wr = wave / WC, wc = wave % WC;
    int lrow = lane & 15, quad = lane >> 4;
    int m0 = blockIdx.y * BM, n0 = blockIdx.x * BNt;

    // staging sources: chunk c, thread i stages 16B at LDS ushort (c*2048 + tid*8)
    // -> row (c*256+tid)>>2, col8 (tid&3)*8.
    const unsigned short* ag0 = A + (size_t)(m0 + (tid >> 2)) * K + (tid & 3) * 8;
    const unsigned short* ag1 = A + (size_t)(m0 + 64 + (tid >> 2)) * K + (tid & 3) * 8;
    const unsigned short* bg0 = Bt + (size_t)(n0 + (tid >> 2)) * K + (tid & 3) * 8;
    const unsigned short* bg1 =
        (BCH == 2) ? (Bt + (size_t)(n0 + 64 + (tid >> 2)) * K + (tid & 3) * 8) : nullptr;

    f32x4 acc[MT][4];
#pragma unroll
    for (int i = 0; i < MT; i++)
#pragma unroll
        for (int j = 0; j < 4; j++) acc[i][j] = (f32x4){0.f, 0.f, 0.f, 0.f};

    auto stage = [&](int buf, int koff) {
        GLOAD16(ag0 + koff, &As[buf][wave * 512]);
        GLOAD16(ag1 + koff, &As[buf][2048 + wave * 512]);
        GLOAD16(bg0 + koff, &Bs[buf][wave * 512]);
        if constexpr (BCH == 2) GLOAD16(bg1 + koff, &Bs[buf][2048 + wave * 512]);
    };

    int ntiles = K / BK;
    stage(0, 0);
    __syncthreads();
    for (int t = 0; t < ntiles; ++t) {
        if (t + 1 < ntiles) stage((t + 1) & 1, (t + 1) * BK);  // prefetch overlaps compute
        int cur = t & 1;
        short8 af[MT], bfr[4];
#pragma unroll
        for (int mt = 0; mt < MT; mt++)
            af[mt] = *(const short8*)&As[cur][(wr * (MT * 16) + mt * 16 + lrow) * BK + quad * 8];
#pragma unroll
        for (int nf = 0; nf < 4; nf++)
            bfr[nf] = *(const short8*)&Bs[cur][(wc * 64 + nf * 16 + lrow) * BK + quad * 8];
#pragma unroll
        for (int mt = 0; mt < MT; mt++)
#pragma unroll
            for (int nf = 0; nf < 4; nf++)
                acc[mt][nf] = __builtin_amdgcn_mfma_f32_16x16x32_bf16(af[mt], bfr[nf],
                                                                     acc[mt][nf], 0, 0, 0);
        __syncthreads();  // staged tile landed; all reads of buf[cur] done
    }

#pragma unroll
    for (int nf = 0; nf < 4; nf++) {
        int gc = n0 + wc * 64 + nf * 16 + lrow;
        float bs = (bias2 && gc >= 128) ? bias2[gc - 128] : (bias ? bias[gc] : 0.f);
        float g = 1.f, bb = 0.f, mm = 0.f, inv = 1.f;
        if (mode == 1) {
            g = bn_g[gc];
            bb = bn_b[gc];
            mm = bn_m[gc];
            inv = rsqrtf(bn_v[gc] + 1e-5f);
        }
        float pg = 0.f, pb = 0.f, pm = 0.f, pinv = 0.f;
        if (mode >= 2 && pn_g) {
            pg = pn_g[gc];
            pb = pn_b[gc];
            pm = pn_m[gc];
            pinv = rsqrtf(pn_v[gc] + 1e-5f);
        }
#pragma unroll
        for (int mt = 0; mt < MT; mt++) {
#pragma unroll
            for (int r = 0; r < 4; r++) {
                int gr = m0 + wr * (MT * 16) + mt * 16 + quad * 4 + r;
                size_t idx = (size_t)gr * N + gc;
                float v = acc[mt][nf][r] + bs;
                if (mode == 0) {
                    CoutB[idx] = f2bf(v);
                } else if (mode == 1) {
                    v = fmaxf(g * (v - mm) * inv + bb, 0.f);
                    CoutB[idx] = f2bf(v);
                } else {
                    if (mode == 2) v += CoutF[idx];
                    CoutF[idx] = v;
                    if (pn_g)
                        Rbuf[idx] = f2bf(fmaxf(pg * (v - pm) * pinv + pb, 0.f));
                }
            }
        }
    }
}

// ---------------- Fused GENConv aggregation ----------------
// z = msg*t with msg>0 and t ~ 0.1 => z bounded (few units); exp(z) cannot overflow,
// and softmax is shift-invariant, so we drop the online-max rescale chain entirely:
// denom = sum exp(z), num = sum msg*exp(z).  Identical math to the reference.

__global__ __launch_bounds__(128) void agg_kernel(
    const unsigned short* __restrict__ xs, int xss,
    const unsigned short* __restrict__ xd, int xds,
    const int* __restrict__ ssrc, const float* __restrict__ sattr,
    const int* __restrict__ off,
    const float* __restrict__ ew, const float* __restrict__ eb,
    const float* __restrict__ tptr, unsigned short* __restrict__ outb) {
    int d = blockIdx.x;
    int hh = threadIdx.x;
    int s0 = off[d], s1 = off[d + 1];
    float w = ew[hh], b = eb[hh];
    float tl = tptr[0];
    float denom = 0.f, num = 0.f;

#define EDGE_STEP(xv, av)                                  \
    {                                                      \
        float msg = fmaxf((xv) + (av)*w + b, 0.f) + 1e-7f; \
        float e = __expf(msg * tl);                        \
        denom += e;                                        \
        num += msg * e;                                    \
    }

    int j = s0;
    for (; j + 3 < s1; j += 4) {
        int i0 = ssrc[j], i1 = ssrc[j + 1], i2 = ssrc[j + 2], i3 = ssrc[j + 3];
        float a0 = sattr[j], a1 = sattr[j + 1], a2 = sattr[j + 2], a3 = sattr[j + 3];
        float x0 = bf2f(xs[(size_t)i0 * xss + hh]);
        float x1 = bf2f(xs[(size_t)i1 * xss + hh]);
        float x2 = bf2f(xs[(size_t)i2 * xss + hh]);
        float x3 = bf2f(xs[(size_t)i3 * xss + hh]);
        EDGE_STEP(x0, a0)
        EDGE_STEP(x1, a1)
        EDGE_STEP(x2, a2)
        EDGE_STEP(x3, a3)
    }
    for (; j < s1; j++) {
        int s = ssrc[j];
        float a = sattr[j];
        float xv = bf2f(xs[(size_t)s * xss + hh]);
        EDGE_STEP(xv, a)
    }
    float agg = (s1 > s0) ? (num / fmaxf(denom, 1e-16f)) : 0.f;
    outb[(size_t)d * Hh + hh] = f2bf(agg + bf2f(xd[(size_t)d * xds + hh]));
#undef EDGE_STEP
}

// ---------------- final norm + hierarchical mean-pool ----------------

#define PCHUNK 100

__global__ __launch_bounds__(128) void pool_kernel(
    const float* __restrict__ h, const int* __restrict__ batch,
    const float* __restrict__ g, const float* __restrict__ b,
    const float* __restrict__ m, const float* __restrict__ v,
    float* __restrict__ pooled, float* __restrict__ cnt) {
    int hh = threadIdx.x;
    int i0 = blockIdx.x * PCHUNK;
    int i1 = min(i0 + PCHUNK, Nn);
    if (i0 >= Nn) return;
    float gg = g[hh], bb = b[hh], mm = m[hh], inv = rsqrtf(v[hh] + 1e-5f);
    int cur = batch[i0];
    float sum = 0.f, c = 0.f;
    for (int i = i0; i < i1; i++) {
        int gid = batch[i];
        float val = fmaxf(gg * (h[(size_t)i * Hh + hh] - mm) * inv + bb, 0.f);
        if (gid != cur) {
            atomicAdd(&pooled[(size_t)cur * Hh + hh], sum);
            if (hh == 0) atomicAdd(&cnt[cur], c);
            cur = gid;
            sum = 0.f;
            c = 0.f;
        }
        sum += val;
        c += 1.f;
    }
    atomicAdd(&pooled[(size_t)cur * Hh + hh], sum);
    if (hh == 0) atomicAdd(&cnt[cur], c);
}

// ---------------- classifier ----------------

__global__ __launch_bounds__(128) void cls_kernel(const float* __restrict__ pooled,
                                                  const float* __restrict__ cnt,
                                                  const float* __restrict__ clinical,
                                                  const float* __restrict__ w,
                                                  const float* __restrict__ bias,
                                                  float* __restrict__ out) {
    int t = threadIdx.x;
    int g = t >> 1, c = t & 1;
    float inv = 1.f / fmaxf(cnt[g], 1.f);
    float s = bias[c];
    for (int j = 0; j < Hh; j++) s += pooled[g * Hh + j] * inv * w[j * NCc + c];
    for (int k = 0; k < Kk; k++) s += clinical[g * Kk + k] * w[(Hh + k) * NCc + c];
    out[g * NCc + c] = s;
}

// ---------------- launch ----------------

extern "C" void kernel_launch(void* const* d_in, const int* in_sizes, int n_in,
                              void* d_out, int out_size, void* d_ws, size_t ws_size,
                              hipStream_t stream) {
    const float* x = (const float*)d_in[0];
    const int* eidx = (const int*)d_in[1];
    const float* eattr = (const float*)d_in[2];
    const int* batch = (const int*)d_in[3];
    const float* clinical = (const float*)d_in[4];
    const float* lin_src_w = (const float*)d_in[5];
    const float* lin_src_b = (const float*)d_in[6];
    const float* lin_dst_w = (const float*)d_in[7];
    const float* lin_dst_b = (const float*)d_in[8];
    const float* edge_w = (const float*)d_in[9];
    const float* edge_b = (const float*)d_in[10];
    const float* tt = (const float*)d_in[11];
    const float* mlp_w1 = (const float*)d_in[12];
    const float* mlp_b1 = (const float*)d_in[13];
    const float* bn_g = (const float*)d_in[14];
    const float* bn_b = (const float*)d_in[15];
    const float* bn_m = (const float*)d_in[16];
    const float* bn_v = (const float*)d_in[17];
    const float* mlp_w2 = (const float*)d_in[18];
    const float* mlp_b2 = (const float*)d_in[19];
    const float* norm_g = (const float*)d_in[20];
    const float* norm_b = (const float*)d_in[21];
    const float* norm_m = (const float*)d_in[22];
    const float* norm_v = (const float*)d_in[23];
    const float* cls_w = (const float*)d_in[24];
    const float* cls_b = (const float*)d_in[25];
    float* out = (float*)d_out;

    const int* src = eidx;
    const int* dst = eidx + Ee;

    char* ws = (char*)d_ws;
    size_t off_b = 0;
    auto alloc = [&](size_t bytes) -> void* {
        void* p = ws + off_b;
        off_b += (bytes + 255) & ~(size_t)255;
        return p;
    };
    // All GEMM-touched buffers padded to MPAD rows (garbage pad rows never read).
    unsigned short* xsd = (unsigned short*)alloc((size_t)MPAD * 256 * 2);   // proj out
    unsigned short* rbuf = (unsigned short*)alloc((size_t)MPAD * Hh * 2);   // prenorm out
    unsigned short* aggout = (unsigned short*)alloc((size_t)MPAD * Hh * 2);
    unsigned short* hmid = (unsigned short*)alloc((size_t)MPAD * 2 * Hh * 2);
    float* hbuf = (float*)alloc((size_t)MPAD * Hh * 4);
    int* deg = (int*)alloc((Nn + 1) * 4);
    int* offp = (int*)alloc((Nn + 1) * 4);
    int* pos = (int*)alloc((size_t)Nn * 4);
    int* bsum = (int*)alloc(NB * 4);
    int* boff = (int*)alloc(NB * 4);
    int* ssrc = (int*)alloc((size_t)Ee * 4);
    float* sattr = (float*)alloc((size_t)Ee * 4);
    float* pooled = (float*)alloc((size_t)Gg * Hh * 4);
    float* cntb = (float*)alloc(Gg * 4);
    unsigned short* wt = (unsigned short*)alloc((size_t)327680 * 2);
    // xbf aliases hmid: proj (reads xbf) completes before w1 writes hmid.
    unsigned short* xbf = hmid;

    hipMemsetAsync(deg, 0, (Nn + 1) * 4, stream);
    hipMemsetAsync(pooled, 0, (size_t)Gg * Hh * 4, stream);
    hipMemsetAsync(cntb, 0, Gg * 4, stream);

    hist_kernel<<<(Ee + 255) / 256, 256, 0, stream>>>(dst, deg);
    bsum_kernel<<<NB, 256, 0, stream>>>(deg, bsum);
    bscan_kernel<<<1, 256, 0, stream>>>(bsum, boff, offp);
    offsets_kernel<<<NB, 256, 0, stream>>>(deg, boff, offp, pos);
    scatter_kernel<<<(Ee + 255) / 256, 256, 0, stream>>>(src, dst, eattr, pos, ssrc, sattr);
    wconv_kernel<<<1280, 256, 0, stream>>>(lin_src_w, lin_dst_w, mlp_w1, mlp_w2, wt);
    xconv_kernel<<<(Nn * Cc / 8 + 255) / 256, 256, 0, stream>>>(x, xbf);

    const unsigned short* wt_proj = wt;
    const unsigned short* wt_w1 = wt + 65536;
    const unsigned short* wt_w2 = wt + 196608;

    // Fused projection: xsd[:, :128] = x@Wsrc+b, xsd[:, 128:] = x@Wdst+b
    dim3 gproj(256 / 128, MPAD / BM);
    gemm_kernel<128><<<gproj, 256, 0, stream>>>(xbf, wt_proj, lin_src_b, lin_dst_b,
                                                nullptr, nullptr, nullptr, nullptr,
                                                nullptr, nullptr, nullptr, nullptr,
                                                nullptr, xsd, nullptr, 256, Cc, 0);

    for (int l = 0; l < Ll; l++) {
        const unsigned short* cxs;
        const unsigned short* cxd;
        int xss, xds;
        if (l == 0) {
            cxs = xsd;
            xss = 256;
            cxd = xsd + 128;
            xds = 256;
        } else {
            // rbuf was produced by previous layer's w2 epilogue (fused prenorm)
            cxs = rbuf;
            xss = Hh;
            cxd = rbuf;
            xds = Hh;
        }
        agg_kernel<<<Nn, 128, 0, stream>>>(cxs, xss, cxd, xds, ssrc, sattr, offp,
                                           edge_w + l * Hh, edge_b + l * Hh, tt + l, aggout);
        dim3 g1((2 * Hh) / 128, MPAD / BM);
        gemm_kernel<128><<<g1, 256, 0, stream>>>(aggout, wt_w1 + (size_t)l * 32768,
                                                 mlp_b1 + l * 2 * Hh, nullptr,
                                                 bn_g + l * 2 * Hh, bn_b + l * 2 * Hh,
                                                 bn_m + l * 2 * Hh, bn_v + l * 2 * Hh,
                                                 nullptr, nullptr, nullptr, nullptr,
                                                 nullptr, hmid, nullptr, 2 * Hh, Hh, 1);
        // w2 epilogue: residual += (mode 2) / store (mode 3, l==0) into hbuf,
        // plus fused prenorm for next layer into rbuf (norm params l+1).
        const float* png = (l < Ll - 1) ? (norm_g + (l + 1) * Hh) : nullptr;
        const float* pnb = (l < Ll - 1) ? (norm_b + (l + 1) * Hh) : nullptr;
        const float* pnm = (l < Ll - 1) ? (norm_m + (l + 1) * Hh) : nullptr;
        const float* pnv = (l < Ll - 1) ? (norm_v + (l + 1) * Hh) : nullptr;
        dim3 g2(Hh / 64, MPAD / BM);  // BN=64 -> 782 blocks (vs 391 at BN=128)
        gemm_kernel<64><<<g2, 256, 0, stream>>>(hmid, wt_w2 + (size_t)l * 32768,
                                                mlp_b2 + l * Hh, nullptr,
                                                nullptr, nullptr, nullptr, nullptr,
                                                png, pnb, pnm, pnv,
                                                hbuf, nullptr, rbuf, Hh, 2 * Hh,
                                                (l == 0) ? 3 : 2);
    }

    pool_kernel<<<(Nn + PCHUNK - 1) / PCHUNK, 128, 0, stream>>>(hbuf, batch, norm_g, norm_b,
                                                                norm_m, norm_v, pooled, cntb);
    cls_kernel<<<1, 128, 0, stream>>>(pooled, cntb, clinical, cls_w, cls_b, out);
}

// Round 3
// 614.103 us; speedup vs baseline: 1.1033x; 1.0264x over previous
//
#include <hip/hip_runtime.h>
#include <math.h>

// Problem constants (from reference)
#define Nn 50000
#define MPAD 50048  // Nn padded to multiple of 128 (GEMM row tiles, no guards)
#define Ee 500000
#define Cc 256
#define Hh 128
#define Ll 4
#define Gg 64
#define Kk 8
#define NCc 2

#define NB 196  // ceil(Nn/256)

typedef __attribute__((ext_vector_type(8))) short short8;
typedef __attribute__((ext_vector_type(4))) float f32x4;

__device__ __forceinline__ unsigned short f2bf(float f) {
    union { float f; unsigned int u; } v;
    v.f = f;
    unsigned int u = v.u;
    return (unsigned short)((u + 0x7FFFu + ((u >> 16) & 1u)) >> 16);
}
__device__ __forceinline__ float bf2f(unsigned short s) {
    union { float f; unsigned int u; } v;
    v.u = ((unsigned int)s) << 16;
    return v.f;
}
__device__ __forceinline__ float bf2f_lo(unsigned int u) {
    union { float f; unsigned int u; } v;
    v.u = u << 16;
    return v.f;
}
__device__ __forceinline__ float bf2f_hi(unsigned int u) {
    union { float f; unsigned int u; } v;
    v.u = u & 0xffff0000u;
    return v.f;
}

// ---------------- CSR build ----------------

__global__ void hist_kernel(const int* __restrict__ dst, int* __restrict__ deg) {
    int e = blockIdx.x * 256 + threadIdx.x;
    if (e < Ee) atomicAdd(&deg[dst[e]], 1);
}

__global__ __launch_bounds__(256) void bsum_kernel(const int* __restrict__ deg,
                                                   int* __restrict__ bsum) {
    __shared__ int ws[4];
    int t = threadIdx.x;
    int i = blockIdx.x * 256 + t;
    int v = (i < Nn) ? deg[i] : 0;
#pragma unroll
    for (int o = 32; o; o >>= 1) v += __shfl_down(v, o, 64);
    if ((t & 63) == 0) ws[t >> 6] = v;
    __syncthreads();
    if (t == 0) bsum[blockIdx.x] = ws[0] + ws[1] + ws[2] + ws[3];
}

__global__ __launch_bounds__(256) void bscan_kernel(const int* __restrict__ bsum,
                                                    int* __restrict__ boff,
                                                    int* __restrict__ off) {
    __shared__ int sc[256];
    int t = threadIdx.x;
    int v = (t < NB) ? bsum[t] : 0;
    sc[t] = v;
    __syncthreads();
    for (int o = 1; o < 256; o <<= 1) {
        int u = (t >= o) ? sc[t - o] : 0;
        __syncthreads();
        sc[t] += u;
        __syncthreads();
    }
    if (t < NB) boff[t] = sc[t] - v;  // exclusive
    if (t == NB - 1) off[Nn] = sc[t];
}

__global__ __launch_bounds__(256) void offsets_kernel(const int* __restrict__ deg,
                                                      const int* __restrict__ boff,
                                                      int* __restrict__ off,
                                                      int* __restrict__ pos) {
    __shared__ int sc[256];
    int t = threadIdx.x;
    int i = blockIdx.x * 256 + t;
    int v = (i < Nn) ? deg[i] : 0;
    sc[t] = v;
    __syncthreads();
    for (int o = 1; o < 256; o <<= 1) {
        int u = (t >= o) ? sc[t - o] : 0;
        __syncthreads();
        sc[t] += u;
        __syncthreads();
    }
    int excl = sc[t] - v + boff[blockIdx.x];
    if (i < Nn) {
        off[i] = excl;
        pos[i] = excl;
    }
}

__global__ void scatter_kernel(const int* __restrict__ src, const int* __restrict__ dst,
                               const float* __restrict__ attr, int* __restrict__ pos,
                               int* __restrict__ ssrc, float* __restrict__ sattr) {
    int e = blockIdx.x * 256 + threadIdx.x;
    if (e < Ee) {
        int d = dst[e];
        int p = atomicAdd(&pos[d], 1);
        ssrc[p] = src[e];
        sattr[p] = attr[e];
    }
}

// ---------------- weight convert + transpose to bf16 [N][K] ----------------
// wt layout: [0, 65536)            proj  [256 n][256 k]  (n<128: lin_src col, else lin_dst)
//            [65536, 196608)       w1[l] [256 n][128 k]
//            [196608, 327680)      w2[l] [128 n][256 k]

__global__ void wconv_kernel(const float* __restrict__ lin_src_w,
                             const float* __restrict__ lin_dst_w,
                             const float* __restrict__ mlp_w1,
                             const float* __restrict__ mlp_w2,
                             unsigned short* __restrict__ wt) {
    int idx = blockIdx.x * 256 + threadIdx.x;
    if (idx >= 327680) return;
    float val;
    if (idx < 65536) {
        int n = idx >> 8, k = idx & 255;
        val = (n < 128) ? lin_src_w[k * 128 + n] : lin_dst_w[k * 128 + (n - 128)];
    } else if (idx < 196608) {
        int r = idx - 65536;
        int l = r >> 15, e = r & 32767;
        int n = e >> 7, k = e & 127;
        val = mlp_w1[(size_t)l * 32768 + k * 256 + n];
    } else {
        int r = idx - 196608;
        int l = r >> 15, e = r & 32767;
        int n = e >> 8, k = e & 255;
        val = mlp_w2[(size_t)l * 32768 + k * 128 + n];
    }
    wt[idx] = f2bf(val);
}

// ---------------- x fp32 -> bf16 (one-time, vectorized) ----------------

__global__ __launch_bounds__(256) void xconv_kernel(const float* __restrict__ x,
                                                    unsigned short* __restrict__ xbf) {
    int idx = blockIdx.x * 256 + threadIdx.x;  // 8 elems per thread
    if (idx >= (Nn * Cc) / 8) return;
    const float4* p = (const float4*)(x) + (size_t)idx * 2;
    float4 v0 = p[0], v1 = p[1];
    unsigned short t[8];
    t[0] = f2bf(v0.x); t[1] = f2bf(v0.y); t[2] = f2bf(v0.z); t[3] = f2bf(v0.w);
    t[4] = f2bf(v1.x); t[5] = f2bf(v1.y); t[6] = f2bf(v1.z); t[7] = f2bf(v1.w);
    *(short8*)(xbf + (size_t)idx * 8) = *(short8*)t;
}

// ---------------- bf16 MFMA GEMM: 128xBNt tile, BK=32, 4 waves,
//                  double-buffered LDS, 2-phase prefetch pipeline (T3-min) ----------------
// C[M,N] = A[M,K](bf16) @ B[N][K](bf16 transposed).  M padded to MPAD, no row guards.
// mode: 0 = bias (+bias2 for cols>=128), store bf16
//       1 = bias + BN + ReLU, store bf16
//       2 = bias + fp32 += CoutF; if pn_*: Rbuf = bf16(relu(BN_pn(new)))
//       3 = bias + fp32 store;   if pn_*: Rbuf = bf16(relu(BN_pn(new)))

#define BM 128
#define BK 32

#define GLOAD16(gp, lp)                                                                       \
    __builtin_amdgcn_global_load_lds(                                                         \
        (const __attribute__((address_space(1))) unsigned int*)(gp),                          \
        (__attribute__((address_space(3))) unsigned int*)(lp), 16, 0, 0)

template <int BNt>
__global__ __launch_bounds__(256) void gemm_kernel(
    const unsigned short* __restrict__ A, const unsigned short* __restrict__ Bt,
    const float* __restrict__ bias, const float* __restrict__ bias2,
    const float* __restrict__ bn_g, const float* __restrict__ bn_b,
    const float* __restrict__ bn_m, const float* __restrict__ bn_v,
    const float* __restrict__ pn_g, const float* __restrict__ pn_b,
    const float* __restrict__ pn_m, const float* __restrict__ pn_v,
    float* __restrict__ CoutF, unsigned short* __restrict__ CoutB,
    unsigned short* __restrict__ Rbuf, int N, int K, int mode) {
    constexpr int WC = BNt / 64;        // wave grid cols (1 or 2)
    constexpr int WR = 4 / WC;          // wave grid rows (4 or 2)
    constexpr int MT = BM / (WR * 16);  // 16-row frags per wave (2 or 4)
    constexpr int BCH = (BNt * BK) / 2048;  // 4KB staging chunks for B (1 or 2)

    __shared__ __align__(16) unsigned short As[2][BM * BK];   // 2 x 8 KB
    __shared__ __align__(16) unsigned short Bs[2][BNt * BK];  // 2 x (4|8) KB

    int tid = threadIdx.x;
    int wave = tid >> 6, lane = tid & 63;
    int wr = wave / WC, wc = wave % WC;
    int lrow = lane & 15, quad = lane >> 4;
    int m0 = blockIdx.y * BM, n0 = blockIdx.x * BNt;

    // staging sources: chunk c, thread i stages 16B at LDS ushort (c*2048 + tid*8)
    // -> row (c*256+tid)>>2, col8 (tid&3)*8.
    const unsigned short* ag0 = A + (size_t)(m0 + (tid >> 2)) * K + (tid & 3) * 8;
    const unsigned short* ag1 = A + (size_t)(m0 + 64 + (tid >> 2)) * K + (tid & 3) * 8;
    const unsigned short* bg0 = Bt + (size_t)(n0 + (tid >> 2)) * K + (tid & 3) * 8;
    const unsigned short* bg1 =
        (BCH == 2) ? (Bt + (size_t)(n0 + 64 + (tid >> 2)) * K + (tid & 3) * 8) : nullptr;

    f32x4 acc[MT][4];
#pragma unroll
    for (int i = 0; i < MT; i++)
#pragma unroll
        for (int j = 0; j < 4; j++) acc[i][j] = (f32x4){0.f, 0.f, 0.f, 0.f};

    auto stage = [&](int buf, int koff) {
        GLOAD16(ag0 + koff, &As[buf][wave * 512]);
        GLOAD16(ag1 + koff, &As[buf][2048 + wave * 512]);
        GLOAD16(bg0 + koff, &Bs[buf][wave * 512]);
        if constexpr (BCH == 2) GLOAD16(bg1 + koff, &Bs[buf][2048 + wave * 512]);
    };

    int ntiles = K / BK;
    stage(0, 0);
    __syncthreads();
    for (int t = 0; t < ntiles; ++t) {
        if (t + 1 < ntiles) stage((t + 1) & 1, (t + 1) * BK);  // prefetch overlaps compute
        int cur = t & 1;
        short8 af[MT], bfr[4];
#pragma unroll
        for (int mt = 0; mt < MT; mt++)
            af[mt] = *(const short8*)&As[cur][(wr * (MT * 16) + mt * 16 + lrow) * BK + quad * 8];
#pragma unroll
        for (int nf = 0; nf < 4; nf++)
            bfr[nf] = *(const short8*)&Bs[cur][(wc * 64 + nf * 16 + lrow) * BK + quad * 8];
#pragma unroll
        for (int mt = 0; mt < MT; mt++)
#pragma unroll
            for (int nf = 0; nf < 4; nf++)
                acc[mt][nf] = __builtin_amdgcn_mfma_f32_16x16x32_bf16(af[mt], bfr[nf],
                                                                     acc[mt][nf], 0, 0, 0);
        __syncthreads();  // staged tile landed; all reads of buf[cur] done
    }

#pragma unroll
    for (int nf = 0; nf < 4; nf++) {
        int gc = n0 + wc * 64 + nf * 16 + lrow;
        float bs = (bias2 && gc >= 128) ? bias2[gc - 128] : (bias ? bias[gc] : 0.f);
        float g = 1.f, bb = 0.f, mm = 0.f, inv = 1.f;
        if (mode == 1) {
            g = bn_g[gc];
            bb = bn_b[gc];
            mm = bn_m[gc];
            inv = rsqrtf(bn_v[gc] + 1e-5f);
        }
        float pg = 0.f, pb = 0.f, pm = 0.f, pinv = 0.f;
        if (mode >= 2 && pn_g) {
            pg = pn_g[gc];
            pb = pn_b[gc];
            pm = pn_m[gc];
            pinv = rsqrtf(pn_v[gc] + 1e-5f);
        }
#pragma unroll
        for (int mt = 0; mt < MT; mt++) {
#pragma unroll
            for (int r = 0; r < 4; r++) {
                int gr = m0 + wr * (MT * 16) + mt * 16 + quad * 4 + r;
                size_t idx = (size_t)gr * N + gc;
                float v = acc[mt][nf][r] + bs;
                if (mode == 0) {
                    CoutB[idx] = f2bf(v);
                } else if (mode == 1) {
                    v = fmaxf(g * (v - mm) * inv + bb, 0.f);
                    CoutB[idx] = f2bf(v);
                } else {
                    if (mode == 2) v += CoutF[idx];
                    CoutF[idx] = v;
                    if (pn_g)
                        Rbuf[idx] = f2bf(fmaxf(pg * (v - pm) * pinv + pb, 0.f));
                }
            }
        }
    }
}

// ---------------- Fused GENConv aggregation ----------------
// z = msg*t with msg>0, t ~ 0.1 => exp cannot overflow; softmax shift-invariance
// lets us drop the online-max chain (validated rounds 2).  One wave per dst node,
// 2 features per lane (packed uint loads: one 256B gather per edge per wave).
// exp(msg*t) = exp2(msg * (t*log2e)) -> single v_exp_f32 per feature.

__global__ __launch_bounds__(256) void agg_kernel(
    const unsigned short* __restrict__ xs, int xss,
    const unsigned short* __restrict__ xd, int xds,
    const int* __restrict__ ssrc, const float* __restrict__ sattr,
    const int* __restrict__ off,
    const float* __restrict__ ew, const float* __restrict__ eb,
    const float* __restrict__ tptr, unsigned short* __restrict__ outb) {
    int wave = threadIdx.x >> 6;
    int lane = threadIdx.x & 63;
    int d = blockIdx.x * 4 + wave;  // Nn % 4 == 0, always < Nn
    int s0 = off[d], s1 = off[d + 1];
    int f0 = lane * 2;
    float2 wv = *(const float2*)(ew + f0);
    float2 bv = *(const float2*)(eb + f0);
    float tl = tptr[0];
    float c = tl * 1.44269504088896f;  // fold t and log2(e) into exp2 scale
    float den0 = 0.f, num0 = 0.f, den1 = 0.f, num1 = 0.f;

#define EDGE2(u, av)                                           \
    {                                                          \
        float x0 = bf2f_lo(u), x1 = bf2f_hi(u);                \
        float m0 = fmaxf(fmaf(av, wv.x, x0 + bv.x), 0.f) + 1e-7f; \
        float m1 = fmaxf(fmaf(av, wv.y, x1 + bv.y), 0.f) + 1e-7f; \
        float e0 = exp2f(m0 * c);                              \
        float e1 = exp2f(m1 * c);                              \
        den0 += e0; num0 = fmaf(m0, e0, num0);                 \
        den1 += e1; num1 = fmaf(m1, e1, num1);                 \
    }

    int j = s0;
    for (; j + 3 < s1; j += 4) {
        int i0 = ssrc[j], i1 = ssrc[j + 1], i2 = ssrc[j + 2], i3 = ssrc[j + 3];
        float a0 = sattr[j], a1 = sattr[j + 1], a2 = sattr[j + 2], a3 = sattr[j + 3];
        unsigned int u0 = *(const unsigned int*)(xs + (size_t)i0 * xss + f0);
        unsigned int u1 = *(const unsigned int*)(xs + (size_t)i1 * xss + f0);
        unsigned int u2 = *(const unsigned int*)(xs + (size_t)i2 * xss + f0);
        unsigned int u3 = *(const unsigned int*)(xs + (size_t)i3 * xss + f0);
        EDGE2(u0, a0)
        EDGE2(u1, a1)
        EDGE2(u2, a2)
        EDGE2(u3, a3)
    }
    for (; j < s1; j++) {
        int s = ssrc[j];
        float a = sattr[j];
        unsigned int u = *(const unsigned int*)(xs + (size_t)s * xss + f0);
        EDGE2(u, a)
    }
#undef EDGE2
    float agg0 = (s1 > s0) ? (num0 / fmaxf(den0, 1e-16f)) : 0.f;
    float agg1 = (s1 > s0) ? (num1 / fmaxf(den1, 1e-16f)) : 0.f;
    unsigned int ud = *(const unsigned int*)(xd + (size_t)d * xds + f0);
    unsigned int lo = f2bf(agg0 + bf2f_lo(ud));
    unsigned int hi = f2bf(agg1 + bf2f_hi(ud));
    *(unsigned int*)(outb + (size_t)d * Hh + f0) = lo | (hi << 16);
}

// ---------------- final norm + hierarchical mean-pool ----------------

#define PCHUNK 100

__global__ __launch_bounds__(128) void pool_kernel(
    const float* __restrict__ h, const int* __restrict__ batch,
    const float* __restrict__ g, const float* __restrict__ b,
    const float* __restrict__ m, const float* __restrict__ v,
    float* __restrict__ pooled, float* __restrict__ cnt) {
    int hh = threadIdx.x;
    int i0 = blockIdx.x * PCHUNK;
    int i1 = min(i0 + PCHUNK, Nn);
    if (i0 >= Nn) return;
    float gg = g[hh], bb = b[hh], mm = m[hh], inv = rsqrtf(v[hh] + 1e-5f);
    int cur = batch[i0];
    float sum = 0.f, c = 0.f;
    for (int i = i0; i < i1; i++) {
        int gid = batch[i];
        float val = fmaxf(gg * (h[(size_t)i * Hh + hh] - mm) * inv + bb, 0.f);
        if (gid != cur) {
            atomicAdd(&pooled[(size_t)cur * Hh + hh], sum);
            if (hh == 0) atomicAdd(&cnt[cur], c);
            cur = gid;
            sum = 0.f;
            c = 0.f;
        }
        sum += val;
        c += 1.f;
    }
    atomicAdd(&pooled[(size_t)cur * Hh + hh], sum);
    if (hh == 0) atomicAdd(&cnt[cur], c);
}

// ---------------- classifier ----------------

__global__ __launch_bounds__(128) void cls_kernel(const float* __restrict__ pooled,
                                                  const float* __restrict__ cnt,
                                                  const float* __restrict__ clinical,
                                                  const float* __restrict__ w,
                                                  const float* __restrict__ bias,
                                                  float* __restrict__ out) {
    int t = threadIdx.x;
    int g = t >> 1, c = t & 1;
    float inv = 1.f / fmaxf(cnt[g], 1.f);
    float s = bias[c];
    for (int j = 0; j < Hh; j++) s += pooled[g * Hh + j] * inv * w[j * NCc + c];
    for (int k = 0; k < Kk; k++) s += clinical[g * Kk + k] * w[(Hh + k) * NCc + c];
    out[g * NCc + c] = s;
}

// ---------------- launch ----------------

extern "C" void kernel_launch(void* const* d_in, const int* in_sizes, int n_in,
                              void* d_out, int out_size, void* d_ws, size_t ws_size,
                              hipStream_t stream) {
    const float* x = (const float*)d_in[0];
    const int* eidx = (const int*)d_in[1];
    const float* eattr = (const float*)d_in[2];
    const int* batch = (const int*)d_in[3];
    const float* clinical = (const float*)d_in[4];
    const float* lin_src_w = (const float*)d_in[5];
    const float* lin_src_b = (const float*)d_in[6];
    const float* lin_dst_w = (const float*)d_in[7];
    const float* lin_dst_b = (const float*)d_in[8];
    const float* edge_w = (const float*)d_in[9];
    const float* edge_b = (const float*)d_in[10];
    const float* tt = (const float*)d_in[11];
    const float* mlp_w1 = (const float*)d_in[12];
    const float* mlp_b1 = (const float*)d_in[13];
    const float* bn_g = (const float*)d_in[14];
    const float* bn_b = (const float*)d_in[15];
    const float* bn_m = (const float*)d_in[16];
    const float* bn_v = (const float*)d_in[17];
    const float* mlp_w2 = (const float*)d_in[18];
    const float* mlp_b2 = (const float*)d_in[19];
    const float* norm_g = (const float*)d_in[20];
    const float* norm_b = (const float*)d_in[21];
    const float* norm_m = (const float*)d_in[22];
    const float* norm_v = (const float*)d_in[23];
    const float* cls_w = (const float*)d_in[24];
    const float* cls_b = (const float*)d_in[25];
    float* out = (float*)d_out;

    const int* src = eidx;
    const int* dst = eidx + Ee;

    char* ws = (char*)d_ws;
    size_t off_b = 0;
    auto alloc = [&](size_t bytes) -> void* {
        void* p = ws + off_b;
        off_b += (bytes + 255) & ~(size_t)255;
        return p;
    };
    // All GEMM-touched buffers padded to MPAD rows (garbage pad rows never read).
    unsigned short* xsd = (unsigned short*)alloc((size_t)MPAD * 256 * 2);   // proj out
    unsigned short* rbuf = (unsigned short*)alloc((size_t)MPAD * Hh * 2);   // prenorm out
    unsigned short* aggout = (unsigned short*)alloc((size_t)MPAD * Hh * 2);
    unsigned short* hmid = (unsigned short*)alloc((size_t)MPAD * 2 * Hh * 2);
    float* hbuf = (float*)alloc((size_t)MPAD * Hh * 4);
    int* deg = (int*)alloc((Nn + 1) * 4);
    int* offp = (int*)alloc((Nn + 1) * 4);
    int* pos = (int*)alloc((size_t)Nn * 4);
    int* bsum = (int*)alloc(NB * 4);
    int* boff = (int*)alloc(NB * 4);
    int* ssrc = (int*)alloc((size_t)Ee * 4);
    float* sattr = (float*)alloc((size_t)Ee * 4);
    float* pooled = (float*)alloc((size_t)Gg * Hh * 4);
    float* cntb = (float*)alloc(Gg * 4);
    unsigned short* wt = (unsigned short*)alloc((size_t)327680 * 2);
    // xbf aliases hmid: proj (reads xbf) completes before w1 writes hmid.
    unsigned short* xbf = hmid;

    hipMemsetAsync(deg, 0, (Nn + 1) * 4, stream);
    hipMemsetAsync(pooled, 0, (size_t)Gg * Hh * 4, stream);
    hipMemsetAsync(cntb, 0, Gg * 4, stream);

    hist_kernel<<<(Ee + 255) / 256, 256, 0, stream>>>(dst, deg);
    bsum_kernel<<<NB, 256, 0, stream>>>(deg, bsum);
    bscan_kernel<<<1, 256, 0, stream>>>(bsum, boff, offp);
    offsets_kernel<<<NB, 256, 0, stream>>>(deg, boff, offp, pos);
    scatter_kernel<<<(Ee + 255) / 256, 256, 0, stream>>>(src, dst, eattr, pos, ssrc, sattr);
    wconv_kernel<<<1280, 256, 0, stream>>>(lin_src_w, lin_dst_w, mlp_w1, mlp_w2, wt);
    xconv_kernel<<<(Nn * Cc / 8 + 255) / 256, 256, 0, stream>>>(x, xbf);

    const unsigned short* wt_proj = wt;
    const unsigned short* wt_w1 = wt + 65536;
    const unsigned short* wt_w2 = wt + 196608;

    // Fused projection: xsd[:, :128] = x@Wsrc+b, xsd[:, 128:] = x@Wdst+b
    dim3 gproj(256 / 128, MPAD / BM);
    gemm_kernel<128><<<gproj, 256, 0, stream>>>(xbf, wt_proj, lin_src_b, lin_dst_b,
                                                nullptr, nullptr, nullptr, nullptr,
                                                nullptr, nullptr, nullptr, nullptr,
                                                nullptr, xsd, nullptr, 256, Cc, 0);

    for (int l = 0; l < Ll; l++) {
        const unsigned short* cxs;
        const unsigned short* cxd;
        int xss, xds;
        if (l == 0) {
            cxs = xsd;
            xss = 256;
            cxd = xsd + 128;
            xds = 256;
        } else {
            // rbuf was produced by previous layer's w2 epilogue (fused prenorm)
            cxs = rbuf;
            xss = Hh;
            cxd = rbuf;
            xds = Hh;
        }
        agg_kernel<<<Nn / 4, 256, 0, stream>>>(cxs, xss, cxd, xds, ssrc, sattr, offp,
                                               edge_w + l * Hh, edge_b + l * Hh, tt + l,
                                               aggout);
        dim3 g1((2 * Hh) / 128, MPAD / BM);
        gemm_kernel<128><<<g1, 256, 0, stream>>>(aggout, wt_w1 + (size_t)l * 32768,
                                                 mlp_b1 + l * 2 * Hh, nullptr,
                                                 bn_g + l * 2 * Hh, bn_b + l * 2 * Hh,
                                                 bn_m + l * 2 * Hh, bn_v + l * 2 * Hh,
                                                 nullptr, nullptr, nullptr, nullptr,
                                                 nullptr, hmid, nullptr, 2 * Hh, Hh, 1);
        // w2 epilogue: residual += (mode 2) / store (mode 3, l==0) into hbuf,
        // plus fused prenorm for next layer into rbuf (norm params l+1).
        const float* png = (l < Ll - 1) ? (norm_g + (l + 1) * Hh) : nullptr;
        const float* pnb = (l < Ll - 1) ? (norm_b + (l + 1) * Hh) : nullptr;
        const float* pnm = (l < Ll - 1) ? (norm_m + (l + 1) * Hh) : nullptr;
        const float* pnv = (l < Ll - 1) ? (norm_v + (l + 1) * Hh) : nullptr;
        dim3 g2(Hh / 64, MPAD / BM);  // BN=64 -> 782 blocks (vs 391 at BN=128)
        gemm_kernel<64><<<g2, 256, 0, stream>>>(hmid, wt_w2 + (size_t)l * 32768,
                                                mlp_b2 + l * Hh, nullptr,
                                                nullptr, nullptr, nullptr, nullptr,
                                                png, pnb, pnm, pnv,
                                                hbuf, nullptr, rbuf, Hh, 2 * Hh,
                                                (l == 0) ? 3 : 2);
    }

    pool_kernel<<<(Nn + PCHUNK - 1) / PCHUNK, 128, 0, stream>>>(hbuf, batch, norm_g, norm_b,
                                                                norm_m, norm_v, pooled, cntb);
    cls_kernel<<<1, 128, 0, stream>>>(pooled, cntb, clinical, cls_w, cls_b, out);
}

// Round 4
// 603.618 us; speedup vs baseline: 1.1224x; 1.0174x over previous
//
#include <hip/hip_runtime.h>
#include <math.h>

// Problem constants (from reference)
#define Nn 50000
#define MPAD 50048  // Nn padded to multiple of 128 (GEMM row tiles, no guards)
#define Ee 500000
#define Cc 256
#define Hh 128
#define Ll 4
#define Gg 64
#define Kk 8
#define NCc 2

#define NB 196  // ceil(Nn/256)

typedef __attribute__((ext_vector_type(8))) short short8;
typedef __attribute__((ext_vector_type(4))) float f32x4;
typedef __attribute__((ext_vector_type(2))) float f32x2;

__device__ __forceinline__ unsigned short f2bf(float f) {
    union { float f; unsigned int u; } v;
    v.f = f;
    unsigned int u = v.u;
    return (unsigned short)((u + 0x7FFFu + ((u >> 16) & 1u)) >> 16);
}
__device__ __forceinline__ float bf2f(unsigned short s) {
    union { float f; unsigned int u; } v;
    v.u = ((unsigned int)s) << 16;
    return v.f;
}
__device__ __forceinline__ float bf2f_lo(unsigned int u) {
    union { float f; unsigned int u; } v;
    v.u = u << 16;
    return v.f;
}
__device__ __forceinline__ float bf2f_hi(unsigned int u) {
    union { float f; unsigned int u; } v;
    v.u = u & 0xffff0000u;
    return v.f;
}

// ---------------- CSR build ----------------

__global__ void hist_kernel(const int* __restrict__ dst, int* __restrict__ deg) {
    int e = blockIdx.x * 256 + threadIdx.x;
    if (e < Ee) atomicAdd(&deg[dst[e]], 1);
}

__global__ __launch_bounds__(256) void bsum_kernel(const int* __restrict__ deg,
                                                   int* __restrict__ bsum) {
    __shared__ int ws[4];
    int t = threadIdx.x;
    int i = blockIdx.x * 256 + t;
    int v = (i < Nn) ? deg[i] : 0;
#pragma unroll
    for (int o = 32; o; o >>= 1) v += __shfl_down(v, o, 64);
    if ((t & 63) == 0) ws[t >> 6] = v;
    __syncthreads();
    if (t == 0) bsum[blockIdx.x] = ws[0] + ws[1] + ws[2] + ws[3];
}

__global__ __launch_bounds__(256) void bscan_kernel(const int* __restrict__ bsum,
                                                    int* __restrict__ boff,
                                                    int* __restrict__ off) {
    __shared__ int sc[256];
    int t = threadIdx.x;
    int v = (t < NB) ? bsum[t] : 0;
    sc[t] = v;
    __syncthreads();
    for (int o = 1; o < 256; o <<= 1) {
        int u = (t >= o) ? sc[t - o] : 0;
        __syncthreads();
        sc[t] += u;
        __syncthreads();
    }
    if (t < NB) boff[t] = sc[t] - v;  // exclusive
    if (t == NB - 1) off[Nn] = sc[t];
}

__global__ __launch_bounds__(256) void offsets_kernel(const int* __restrict__ deg,
                                                      const int* __restrict__ boff,
                                                      int* __restrict__ off,
                                                      int* __restrict__ pos) {
    __shared__ int sc[256];
    int t = threadIdx.x;
    int i = blockIdx.x * 256 + t;
    int v = (i < Nn) ? deg[i] : 0;
    sc[t] = v;
    __syncthreads();
    for (int o = 1; o < 256; o <<= 1) {
        int u = (t >= o) ? sc[t - o] : 0;
        __syncthreads();
        sc[t] += u;
        __syncthreads();
    }
    int excl = sc[t] - v + boff[blockIdx.x];
    if (i < Nn) {
        off[i] = excl;
        pos[i] = excl;
    }
}

__global__ void scatter_kernel(const int* __restrict__ src, const int* __restrict__ dst,
                               const float* __restrict__ attr, int* __restrict__ pos,
                               int2* __restrict__ sedge) {
    int e = blockIdx.x * 256 + threadIdx.x;
    if (e < Ee) {
        int d = dst[e];
        int p = atomicAdd(&pos[d], 1);
        sedge[p] = make_int2(src[e], __float_as_int(attr[e]));
    }
}

// ---------------- weight convert + transpose to bf16 [N][K] ----------------
// wt layout: [0, 65536)            proj  [256 n][256 k]  (n<128: lin_src col, else lin_dst)
//            [65536, 196608)       w1[l] [256 n][128 k]
//            [196608, 327680)      w2[l] [128 n][256 k]

__global__ void wconv_kernel(const float* __restrict__ lin_src_w,
                             const float* __restrict__ lin_dst_w,
                             const float* __restrict__ mlp_w1,
                             const float* __restrict__ mlp_w2,
                             unsigned short* __restrict__ wt) {
    int idx = blockIdx.x * 256 + threadIdx.x;
    if (idx >= 327680) return;
    float val;
    if (idx < 65536) {
        int n = idx >> 8, k = idx & 255;
        val = (n < 128) ? lin_src_w[k * 128 + n] : lin_dst_w[k * 128 + (n - 128)];
    } else if (idx < 196608) {
        int r = idx - 65536;
        int l = r >> 15, e = r & 32767;
        int n = e >> 7, k = e & 127;
        val = mlp_w1[(size_t)l * 32768 + k * 256 + n];
    } else {
        int r = idx - 196608;
        int l = r >> 15, e = r & 32767;
        int n = e >> 8, k = e & 255;
        val = mlp_w2[(size_t)l * 32768 + k * 128 + n];
    }
    wt[idx] = f2bf(val);
}

// ---------------- x fp32 -> bf16 (one-time, vectorized) ----------------

__global__ __launch_bounds__(256) void xconv_kernel(const float* __restrict__ x,
                                                    unsigned short* __restrict__ xbf) {
    int idx = blockIdx.x * 256 + threadIdx.x;  // 8 elems per thread
    if (idx >= (Nn * Cc) / 8) return;
    const float4* p = (const float4*)(x) + (size_t)idx * 2;
    float4 v0 = p[0], v1 = p[1];
    unsigned short t[8];
    t[0] = f2bf(v0.x); t[1] = f2bf(v0.y); t[2] = f2bf(v0.z); t[3] = f2bf(v0.w);
    t[4] = f2bf(v1.x); t[5] = f2bf(v1.y); t[6] = f2bf(v1.z); t[7] = f2bf(v1.w);
    *(short8*)(xbf + (size_t)idx * 8) = *(short8*)t;
}

// ---------------- bf16 MFMA GEMM: 128xBNt tile, BK=32, 4 waves,
//                  double-buffered LDS, 2-phase prefetch pipeline (T3-min) ----------------
// C[M,N] = A[M,K](bf16) @ B[N][K](bf16 transposed).  M padded to MPAD, no row guards.
// mode: 0 = bias (+bias2 for cols>=128), store bf16
//       1 = bias + BN + ReLU, store bf16
//       2 = bias + fp32 += CoutF; if pn_*: Rbuf = bf16(relu(BN_pn(new)))
//       3 = bias + fp32 store;   if pn_*: Rbuf = bf16(relu(BN_pn(new)))

#define BM 128
#define BK 32

#define GLOAD16(gp, lp)                                                                       \
    __builtin_amdgcn_global_load_lds(                                                         \
        (const __attribute__((address_space(1))) unsigned int*)(gp),                          \
        (__attribute__((address_space(3))) unsigned int*)(lp), 16, 0, 0)

template <int BNt>
__global__ __launch_bounds__(256) void gemm_kernel(
    const unsigned short* __restrict__ A, const unsigned short* __restrict__ Bt,
    const float* __restrict__ bias, const float* __restrict__ bias2,
    const float* __restrict__ bn_g, const float* __restrict__ bn_b,
    const float* __restrict__ bn_m, const float* __restrict__ bn_v,
    const float* __restrict__ pn_g, const float* __restrict__ pn_b,
    const float* __restrict__ pn_m, const float* __restrict__ pn_v,
    float* __restrict__ CoutF, unsigned short* __restrict__ CoutB,
    unsigned short* __restrict__ Rbuf, int N, int K, int mode) {
    constexpr int WC = BNt / 64;        // wave grid cols (1 or 2)
    constexpr int WR = 4 / WC;          // wave grid rows (4 or 2)
    constexpr int MT = BM / (WR * 16);  // 16-row frags per wave (2 or 4)
    constexpr int BCH = (BNt * BK) / 2048;  // 4KB staging chunks for B (1 or 2)

    __shared__ __align__(16) unsigned short As[2][BM * BK];   // 2 x 8 KB
    __shared__ __align__(16) unsigned short Bs[2][BNt * BK];  // 2 x (4|8) KB

    int tid = threadIdx.x;
    int wave = tid >> 6, lane = tid & 63;
    int wr = wave / WC, wc = wave % WC;
    int lrow = lane & 15, quad = lane >> 4;
    int m0 = blockIdx.y * BM, n0 = blockIdx.x * BNt;

    // staging sources: chunk c, thread i stages 16B at LDS ushort (c*2048 + tid*8)
    // -> row (c*256+tid)>>2, col8 (tid&3)*8.
    const unsigned short* ag0 = A + (size_t)(m0 + (tid >> 2)) * K + (tid & 3) * 8;
    const unsigned short* ag1 = A + (size_t)(m0 + 64 + (tid >> 2)) * K + (tid & 3) * 8;
    const unsigned short* bg0 = Bt + (size_t)(n0 + (tid >> 2)) * K + (tid & 3) * 8;
    const unsigned short* bg1 =
        (BCH == 2) ? (Bt + (size_t)(n0 + 64 + (tid >> 2)) * K + (tid & 3) * 8) : nullptr;

    f32x4 acc[MT][4];
#pragma unroll
    for (int i = 0; i < MT; i++)
#pragma unroll
        for (int j = 0; j < 4; j++) acc[i][j] = (f32x4){0.f, 0.f, 0.f, 0.f};

    auto stage = [&](int buf, int koff) {
        GLOAD16(ag0 + koff, &As[buf][wave * 512]);
        GLOAD16(ag1 + koff, &As[buf][2048 + wave * 512]);
        GLOAD16(bg0 + koff, &Bs[buf][wave * 512]);
        if constexpr (BCH == 2) GLOAD16(bg1 + koff, &Bs[buf][2048 + wave * 512]);
    };

    int ntiles = K / BK;
    stage(0, 0);
    __syncthreads();
    for (int t = 0; t < ntiles; ++t) {
        if (t + 1 < ntiles) stage((t + 1) & 1, (t + 1) * BK);  // prefetch overlaps compute
        int cur = t & 1;
        short8 af[MT], bfr[4];
#pragma unroll
        for (int mt = 0; mt < MT; mt++)
            af[mt] = *(const short8*)&As[cur][(wr * (MT * 16) + mt * 16 + lrow) * BK + quad * 8];
#pragma unroll
        for (int nf = 0; nf < 4; nf++)
            bfr[nf] = *(const short8*)&Bs[cur][(wc * 64 + nf * 16 + lrow) * BK + quad * 8];
#pragma unroll
        for (int mt = 0; mt < MT; mt++)
#pragma unroll
            for (int nf = 0; nf < 4; nf++)
                acc[mt][nf] = __builtin_amdgcn_mfma_f32_16x16x32_bf16(af[mt], bfr[nf],
                                                                     acc[mt][nf], 0, 0, 0);
        __syncthreads();  // staged tile landed; all reads of buf[cur] done
    }

#pragma unroll
    for (int nf = 0; nf < 4; nf++) {
        int gc = n0 + wc * 64 + nf * 16 + lrow;
        float bs = (bias2 && gc >= 128) ? bias2[gc - 128] : (bias ? bias[gc] : 0.f);
        float g = 1.f, bb = 0.f, mm = 0.f, inv = 1.f;
        if (mode == 1) {
            g = bn_g[gc];
            bb = bn_b[gc];
            mm = bn_m[gc];
            inv = rsqrtf(bn_v[gc] + 1e-5f);
        }
        float pg = 0.f, pb = 0.f, pm = 0.f, pinv = 0.f;
        if (mode >= 2 && pn_g) {
            pg = pn_g[gc];
            pb = pn_b[gc];
            pm = pn_m[gc];
            pinv = rsqrtf(pn_v[gc] + 1e-5f);
        }
#pragma unroll
        for (int mt = 0; mt < MT; mt++) {
#pragma unroll
            for (int r = 0; r < 4; r++) {
                int gr = m0 + wr * (MT * 16) + mt * 16 + quad * 4 + r;
                size_t idx = (size_t)gr * N + gc;
                float v = acc[mt][nf][r] + bs;
                if (mode == 0) {
                    CoutB[idx] = f2bf(v);
                } else if (mode == 1) {
                    v = fmaxf(g * (v - mm) * inv + bb, 0.f);
                    CoutB[idx] = f2bf(v);
                } else {
                    if (mode == 2) v += CoutF[idx];
                    CoutF[idx] = v;
                    if (pn_g)
                        Rbuf[idx] = f2bf(fmaxf(pg * (v - pm) * pinv + pb, 0.f));
                }
            }
        }
    }
}

// ---------------- Fused GENConv aggregation ----------------
// One wave per dst node, 2 features per lane (one packed-uint 256B gather per edge).
// Softmax shift-invariance (z = msg*t, msg>0, t~0.1 -> no overflow) lets us skip the
// online-max chain (validated rounds 2-3).  Per-edge math on f32x2 so the compiler
// emits packed VOP3P (v_pk_add/fma/mul/max_f32); exp via raw v_exp_f32 (arg bounded,
// no libm fixup needed).  Edge (src,attr) fused into one int2 load.

template <int XSS>
__global__ __launch_bounds__(256) void agg_kernel(
    const unsigned short* __restrict__ xs,
    const unsigned short* __restrict__ xd, int xds,
    const int2* __restrict__ sedge, const int* __restrict__ off,
    const float* __restrict__ ew, const float* __restrict__ eb,
    const float* __restrict__ tptr, unsigned short* __restrict__ outb) {
    int wave = threadIdx.x >> 6;
    int lane = threadIdx.x & 63;
    int d = blockIdx.x * 4 + wave;  // Nn % 4 == 0, always < Nn
    int s0 = off[d], s1 = off[d + 1];
    int f0 = lane * 2;
    f32x2 wv = *(const f32x2*)(ew + f0);
    f32x2 bv = *(const f32x2*)(eb + f0);
    float c = tptr[0] * 1.44269504088896f;  // fold t and log2(e) into exp2 scale
    const f32x2 zz = {0.f, 0.f};
    const f32x2 ee = {1e-7f, 1e-7f};
    f32x2 den = {0.f, 0.f}, num = {0.f, 0.f};

#define EDGE2(u, av)                                                      \
    {                                                                     \
        f32x2 xv = {bf2f_lo(u), bf2f_hi(u)};                              \
        f32x2 m = __builtin_elementwise_max(xv + bv + (av)*wv, zz) + ee;  \
        f32x2 e;                                                          \
        e.x = __builtin_amdgcn_exp2f(m.x * c);                            \
        e.y = __builtin_amdgcn_exp2f(m.y * c);                            \
        den += e;                                                         \
        num += m * e;                                                     \
    }

    int j = s0;
    for (; j + 3 < s1; j += 4) {
        int2 p0 = sedge[j], p1 = sedge[j + 1], p2 = sedge[j + 2], p3 = sedge[j + 3];
        unsigned int u0 = *(const unsigned int*)(xs + (size_t)p0.x * XSS + f0);
        unsigned int u1 = *(const unsigned int*)(xs + (size_t)p1.x * XSS + f0);
        unsigned int u2 = *(const unsigned int*)(xs + (size_t)p2.x * XSS + f0);
        unsigned int u3 = *(const unsigned int*)(xs + (size_t)p3.x * XSS + f0);
        EDGE2(u0, __int_as_float(p0.y))
        EDGE2(u1, __int_as_float(p1.y))
        EDGE2(u2, __int_as_float(p2.y))
        EDGE2(u3, __int_as_float(p3.y))
    }
    for (; j < s1; j++) {
        int2 p = sedge[j];
        unsigned int u = *(const unsigned int*)(xs + (size_t)p.x * XSS + f0);
        EDGE2(u, __int_as_float(p.y))
    }
#undef EDGE2
    float a0 = (s1 > s0) ? (num.x / fmaxf(den.x, 1e-16f)) : 0.f;
    float a1 = (s1 > s0) ? (num.y / fmaxf(den.y, 1e-16f)) : 0.f;
    unsigned int ud = *(const unsigned int*)(xd + (size_t)d * xds + f0);
    unsigned int lo = f2bf(a0 + bf2f_lo(ud));
    unsigned int hi = f2bf(a1 + bf2f_hi(ud));
    *(unsigned int*)(outb + (size_t)d * Hh + f0) = lo | (hi << 16);
}

// ---------------- final norm + hierarchical mean-pool ----------------

#define PCHUNK 100

__global__ __launch_bounds__(128) void pool_kernel(
    const float* __restrict__ h, const int* __restrict__ batch,
    const float* __restrict__ g, const float* __restrict__ b,
    const float* __restrict__ m, const float* __restrict__ v,
    float* __restrict__ pooled, float* __restrict__ cnt) {
    int hh = threadIdx.x;
    int i0 = blockIdx.x * PCHUNK;
    int i1 = min(i0 + PCHUNK, Nn);
    if (i0 >= Nn) return;
    float gg = g[hh], bb = b[hh], mm = m[hh], inv = rsqrtf(v[hh] + 1e-5f);
    int cur = batch[i0];
    float sum = 0.f, c = 0.f;
    for (int i = i0; i < i1; i++) {
        int gid = batch[i];
        float val = fmaxf(gg * (h[(size_t)i * Hh + hh] - mm) * inv + bb, 0.f);
        if (gid != cur) {
            atomicAdd(&pooled[(size_t)cur * Hh + hh], sum);
            if (hh == 0) atomicAdd(&cnt[cur], c);
            cur = gid;
            sum = 0.f;
            c = 0.f;
        }
        sum += val;
        c += 1.f;
    }
    atomicAdd(&pooled[(size_t)cur * Hh + hh], sum);
    if (hh == 0) atomicAdd(&cnt[cur], c);
}

// ---------------- classifier ----------------

__global__ __launch_bounds__(128) void cls_kernel(const float* __restrict__ pooled,
                                                  const float* __restrict__ cnt,
                                                  const float* __restrict__ clinical,
                                                  const float* __restrict__ w,
                                                  const float* __restrict__ bias,
                                                  float* __restrict__ out) {
    int t = threadIdx.x;
    int g = t >> 1, c = t & 1;
    float inv = 1.f / fmaxf(cnt[g], 1.f);
    float s = bias[c];
    for (int j = 0; j < Hh; j++) s += pooled[g * Hh + j] * inv * w[j * NCc + c];
    for (int k = 0; k < Kk; k++) s += clinical[g * Kk + k] * w[(Hh + k) * NCc + c];
    out[g * NCc + c] = s;
}

// ---------------- launch ----------------

extern "C" void kernel_launch(void* const* d_in, const int* in_sizes, int n_in,
                              void* d_out, int out_size, void* d_ws, size_t ws_size,
                              hipStream_t stream) {
    const float* x = (const float*)d_in[0];
    const int* eidx = (const int*)d_in[1];
    const float* eattr = (const float*)d_in[2];
    const int* batch = (const int*)d_in[3];
    const float* clinical = (const float*)d_in[4];
    const float* lin_src_w = (const float*)d_in[5];
    const float* lin_src_b = (const float*)d_in[6];
    const float* lin_dst_w = (const float*)d_in[7];
    const float* lin_dst_b = (const float*)d_in[8];
    const float* edge_w = (const float*)d_in[9];
    const float* edge_b = (const float*)d_in[10];
    const float* tt = (const float*)d_in[11];
    const float* mlp_w1 = (const float*)d_in[12];
    const float* mlp_b1 = (const float*)d_in[13];
    const float* bn_g = (const float*)d_in[14];
    const float* bn_b = (const float*)d_in[15];
    const float* bn_m = (const float*)d_in[16];
    const float* bn_v = (const float*)d_in[17];
    const float* mlp_w2 = (const float*)d_in[18];
    const float* mlp_b2 = (const float*)d_in[19];
    const float* norm_g = (const float*)d_in[20];
    const float* norm_b = (const float*)d_in[21];
    const float* norm_m = (const float*)d_in[22];
    const float* norm_v = (const float*)d_in[23];
    const float* cls_w = (const float*)d_in[24];
    const float* cls_b = (const float*)d_in[25];
    float* out = (float*)d_out;

    const int* src = eidx;
    const int* dst = eidx + Ee;

    char* ws = (char*)d_ws;
    size_t off_b = 0;
    auto alloc = [&](size_t bytes) -> void* {
        void* p = ws + off_b;
        off_b += (bytes + 255) & ~(size_t)255;
        return p;
    };
    // All GEMM-touched buffers padded to MPAD rows (garbage pad rows never read).
    unsigned short* xsd = (unsigned short*)alloc((size_t)MPAD * 256 * 2);   // proj out
    unsigned short* rbuf = (unsigned short*)alloc((size_t)MPAD * Hh * 2);   // prenorm out
    unsigned short* aggout = (unsigned short*)alloc((size_t)MPAD * Hh * 2);
    unsigned short* hmid = (unsigned short*)alloc((size_t)MPAD * 2 * Hh * 2);
    float* hbuf = (float*)alloc((size_t)MPAD * Hh * 4);
    int* deg = (int*)alloc((Nn + 1) * 4);
    int* offp = (int*)alloc((Nn + 1) * 4);
    int* pos = (int*)alloc((size_t)Nn * 4);
    int* bsum = (int*)alloc(NB * 4);
    int* boff = (int*)alloc(NB * 4);
    int2* sedge = (int2*)alloc((size_t)Ee * 8);
    float* pooled = (float*)alloc((size_t)Gg * Hh * 4);
    float* cntb = (float*)alloc(Gg * 4);
    unsigned short* wt = (unsigned short*)alloc((size_t)327680 * 2);
    // xbf aliases hmid: proj (reads xbf) completes before w1 writes hmid.
    unsigned short* xbf = hmid;

    hipMemsetAsync(deg, 0, (Nn + 1) * 4, stream);
    hipMemsetAsync(pooled, 0, (size_t)Gg * Hh * 4, stream);
    hipMemsetAsync(cntb, 0, Gg * 4, stream);

    hist_kernel<<<(Ee + 255) / 256, 256, 0, stream>>>(dst, deg);
    bsum_kernel<<<NB, 256, 0, stream>>>(deg, bsum);
    bscan_kernel<<<1, 256, 0, stream>>>(bsum, boff, offp);
    offsets_kernel<<<NB, 256, 0, stream>>>(deg, boff, offp, pos);
    scatter_kernel<<<(Ee + 255) / 256, 256, 0, stream>>>(src, dst, eattr, pos, sedge);
    wconv_kernel<<<1280, 256, 0, stream>>>(lin_src_w, lin_dst_w, mlp_w1, mlp_w2, wt);
    xconv_kernel<<<(Nn * Cc / 8 + 255) / 256, 256, 0, stream>>>(x, xbf);

    const unsigned short* wt_proj = wt;
    const unsigned short* wt_w1 = wt + 65536;
    const unsigned short* wt_w2 = wt + 196608;

    // Fused projection: xsd[:, :128] = x@Wsrc+b, xsd[:, 128:] = x@Wdst+b
    dim3 gproj(256 / 128, MPAD / BM);
    gemm_kernel<128><<<gproj, 256, 0, stream>>>(xbf, wt_proj, lin_src_b, lin_dst_b,
                                                nullptr, nullptr, nullptr, nullptr,
                                                nullptr, nullptr, nullptr, nullptr,
                                                nullptr, xsd, nullptr, 256, Cc, 0);

    for (int l = 0; l < Ll; l++) {
        if (l == 0) {
            agg_kernel<256><<<Nn / 4, 256, 0, stream>>>(xsd, xsd + 128, 256, sedge, offp,
                                                        edge_w + l * Hh, edge_b + l * Hh,
                                                        tt + l, aggout);
        } else {
            // rbuf was produced by previous layer's w2 epilogue (fused prenorm)
            agg_kernel<128><<<Nn / 4, 256, 0, stream>>>(rbuf, rbuf, Hh, sedge, offp,
                                                        edge_w + l * Hh, edge_b + l * Hh,
                                                        tt + l, aggout);
        }
        dim3 g1((2 * Hh) / 128, MPAD / BM);
        gemm_kernel<128><<<g1, 256, 0, stream>>>(aggout, wt_w1 + (size_t)l * 32768,
                                                 mlp_b1 + l * 2 * Hh, nullptr,
                                                 bn_g + l * 2 * Hh, bn_b + l * 2 * Hh,
                                                 bn_m + l * 2 * Hh, bn_v + l * 2 * Hh,
                                                 nullptr, nullptr, nullptr, nullptr,
                                                 nullptr, hmid, nullptr, 2 * Hh, Hh, 1);
        // w2 epilogue: residual += (mode 2) / store (mode 3, l==0) into hbuf,
        // plus fused prenorm for next layer into rbuf (norm params l+1).
        const float* png = (l < Ll - 1) ? (norm_g + (l + 1) * Hh) : nullptr;
        const float* pnb = (l < Ll - 1) ? (norm_b + (l + 1) * Hh) : nullptr;
        const float* pnm = (l < Ll - 1) ? (norm_m + (l + 1) * Hh) : nullptr;
        const float* pnv = (l < Ll - 1) ? (norm_v + (l + 1) * Hh) : nullptr;
        dim3 g2(Hh / 64, MPAD / BM);  // BN=64 -> 782 blocks (vs 391 at BN=128)
        gemm_kernel<64><<<g2, 256, 0, stream>>>(hmid, wt_w2 + (size_t)l * 32768,
                                                mlp_b2 + l * Hh, nullptr,
                                                nullptr, nullptr, nullptr, nullptr,
                                                png, pnb, pnm, pnv,
                                                hbuf, nullptr, rbuf, Hh, 2 * Hh,
                                                (l == 0) ? 3 : 2);
    }

    pool_kernel<<<(Nn + PCHUNK - 1) / PCHUNK, 128, 0, stream>>>(hbuf, batch, norm_g, norm_b,
                                                                norm_m, norm_v, pooled, cntb);
    cls_kernel<<<1, 128, 0, stream>>>(pooled, cntb, clinical, cls_w, cls_b, out);
}

// Round 5
// 596.569 us; speedup vs baseline: 1.1357x; 1.0118x over previous
//
#include <hip/hip_runtime.h>
#include <math.h>

// Problem constants (from reference)
#define Nn 50000
#define MPAD 50048  // Nn padded to multiple of 128 (GEMM row tiles, no guards)
#define Ee 500000
#define Cc 256
#define Hh 128
#define Ll 4
#define Gg 64
#define Kk 8
#define NCc 2

#define NB 196  // ceil(Nn/256)

typedef __attribute__((ext_vector_type(8))) short short8;
typedef __attribute__((ext_vector_type(4))) float f32x4;
typedef __attribute__((ext_vector_type(2))) float f32x2;

__device__ __forceinline__ unsigned short f2bf(float f) {
    union { float f; unsigned int u; } v;
    v.f = f;
    unsigned int u = v.u;
    return (unsigned short)((u + 0x7FFFu + ((u >> 16) & 1u)) >> 16);
}
__device__ __forceinline__ float bf2f(unsigned short s) {
    union { float f; unsigned int u; } v;
    v.u = ((unsigned int)s) << 16;
    return v.f;
}
__device__ __forceinline__ float bf2f_lo(unsigned int u) {
    union { float f; unsigned int u; } v;
    v.u = u << 16;
    return v.f;
}
__device__ __forceinline__ float bf2f_hi(unsigned int u) {
    union { float f; unsigned int u; } v;
    v.u = u & 0xffff0000u;
    return v.f;
}

// ---------------- CSR build ----------------

__global__ void hist_kernel(const int* __restrict__ dst, int* __restrict__ deg) {
    int e = blockIdx.x * 256 + threadIdx.x;
    if (e < Ee) atomicAdd(&deg[dst[e]], 1);
}

__global__ __launch_bounds__(256) void bsum_kernel(const int* __restrict__ deg,
                                                   int* __restrict__ bsum) {
    __shared__ int ws[4];
    int t = threadIdx.x;
    int i = blockIdx.x * 256 + t;
    int v = (i < Nn) ? deg[i] : 0;
#pragma unroll
    for (int o = 32; o; o >>= 1) v += __shfl_down(v, o, 64);
    if ((t & 63) == 0) ws[t >> 6] = v;
    __syncthreads();
    if (t == 0) bsum[blockIdx.x] = ws[0] + ws[1] + ws[2] + ws[3];
}

__global__ __launch_bounds__(256) void bscan_kernel(const int* __restrict__ bsum,
                                                    int* __restrict__ boff,
                                                    int* __restrict__ off) {
    __shared__ int sc[256];
    int t = threadIdx.x;
    int v = (t < NB) ? bsum[t] : 0;
    sc[t] = v;
    __syncthreads();
    for (int o = 1; o < 256; o <<= 1) {
        int u = (t >= o) ? sc[t - o] : 0;
        __syncthreads();
        sc[t] += u;
        __syncthreads();
    }
    if (t < NB) boff[t] = sc[t] - v;  // exclusive
    if (t == NB - 1) off[Nn] = sc[t];
}

__global__ __launch_bounds__(256) void offsets_kernel(const int* __restrict__ deg,
                                                      const int* __restrict__ boff,
                                                      int* __restrict__ off,
                                                      int* __restrict__ pos) {
    __shared__ int sc[256];
    int t = threadIdx.x;
    int i = blockIdx.x * 256 + t;
    int v = (i < Nn) ? deg[i] : 0;
    sc[t] = v;
    __syncthreads();
    for (int o = 1; o < 256; o <<= 1) {
        int u = (t >= o) ? sc[t - o] : 0;
        __syncthreads();
        sc[t] += u;
        __syncthreads();
    }
    int excl = sc[t] - v + boff[blockIdx.x];
    if (i < Nn) {
        off[i] = excl;
        pos[i] = excl;
    }
}

__global__ void scatter_kernel(const int* __restrict__ src, const int* __restrict__ dst,
                               const float* __restrict__ attr, int* __restrict__ pos,
                               int2* __restrict__ sedge) {
    int e = blockIdx.x * 256 + threadIdx.x;
    if (e < Ee) {
        int d = dst[e];
        int p = atomicAdd(&pos[d], 1);
        sedge[p] = make_int2(src[e], __float_as_int(attr[e]));
    }
}

// ---------------- weight convert + transpose to bf16 [N][K] ----------------
// wt layout: [0, 65536)            proj  [256 n][256 k]  (n<128: lin_src col, else lin_dst)
//            [65536, 196608)       w1[l] [256 n][128 k]
//            [196608, 327680)      w2[l] [128 n][256 k]

__global__ void wconv_kernel(const float* __restrict__ lin_src_w,
                             const float* __restrict__ lin_dst_w,
                             const float* __restrict__ mlp_w1,
                             const float* __restrict__ mlp_w2,
                             unsigned short* __restrict__ wt) {
    int idx = blockIdx.x * 256 + threadIdx.x;
    if (idx >= 327680) return;
    float val;
    if (idx < 65536) {
        int n = idx >> 8, k = idx & 255;
        val = (n < 128) ? lin_src_w[k * 128 + n] : lin_dst_w[k * 128 + (n - 128)];
    } else if (idx < 196608) {
        int r = idx - 65536;
        int l = r >> 15, e = r & 32767;
        int n = e >> 7, k = e & 127;
        val = mlp_w1[(size_t)l * 32768 + k * 256 + n];
    } else {
        int r = idx - 196608;
        int l = r >> 15, e = r & 32767;
        int n = e >> 8, k = e & 255;
        val = mlp_w2[(size_t)l * 32768 + k * 128 + n];
    }
    wt[idx] = f2bf(val);
}

// ---------------- x fp32 -> bf16 (one-time, vectorized) ----------------

__global__ __launch_bounds__(256) void xconv_kernel(const float* __restrict__ x,
                                                    unsigned short* __restrict__ xbf) {
    int idx = blockIdx.x * 256 + threadIdx.x;  // 8 elems per thread
    if (idx >= (Nn * Cc) / 8) return;
    const float4* p = (const float4*)(x) + (size_t)idx * 2;
    float4 v0 = p[0], v1 = p[1];
    unsigned short t[8];
    t[0] = f2bf(v0.x); t[1] = f2bf(v0.y); t[2] = f2bf(v0.z); t[3] = f2bf(v0.w);
    t[4] = f2bf(v1.x); t[5] = f2bf(v1.y); t[6] = f2bf(v1.z); t[7] = f2bf(v1.w);
    *(short8*)(xbf + (size_t)idx * 8) = *(short8*)t;
}

// ---------------- bf16 MFMA GEMM: 128xBNt tile, BK=32, 4 waves ----------------
// Depth-2 prefetch pipeline (T3+T4): triple-buffered LDS, counted vmcnt, ONE
// fused {s_waitcnt vmcnt(N); s_barrier} per K-tile.  Trace (LPT = VMEM ops per
// tile per wave): prologue issues T0,T1; iter t waits vmcnt(LPT) -> oldest tile
// (T_t) landed, T_{t+1} still in flight; barrier; issue T_{t+2}; ds_read+MFMA.
// Buffer (t+2)%3 was last read at iter t-1, whose readers passed this barrier.
// C[M,N] = A[M,K](bf16) @ B[N][K](bf16 transposed).  M padded to MPAD, no guards.
// mode: 0 = bias (+bias2 for cols>=128), store bf16
//       1 = bias + BN + ReLU, store bf16
//       2 = bias + fp32 += CoutF; if pn_*: Rbuf = bf16(relu(BN_pn(new)))
//       3 = bias + fp32 store;   if pn_*: Rbuf = bf16(relu(BN_pn(new)))

#define BM 128
#define BK 32

#define GLOAD16(gp, lp)                                                                       \
    __builtin_amdgcn_global_load_lds(                                                         \
        (const __attribute__((address_space(1))) unsigned int*)(gp),                          \
        (__attribute__((address_space(3))) unsigned int*)(lp), 16, 0, 0)

template <int BNt>
__global__ __launch_bounds__(256) void gemm_kernel(
    const unsigned short* __restrict__ A, const unsigned short* __restrict__ Bt,
    const float* __restrict__ bias, const float* __restrict__ bias2,
    const float* __restrict__ bn_g, const float* __restrict__ bn_b,
    const float* __restrict__ bn_m, const float* __restrict__ bn_v,
    const float* __restrict__ pn_g, const float* __restrict__ pn_b,
    const float* __restrict__ pn_m, const float* __restrict__ pn_v,
    float* __restrict__ CoutF, unsigned short* __restrict__ CoutB,
    unsigned short* __restrict__ Rbuf, int N, int K, int mode) {
    constexpr int WC = BNt / 64;        // wave grid cols (1 or 2)
    constexpr int WR = 4 / WC;          // wave grid rows (4 or 2)
    constexpr int MT = BM / (WR * 16);  // 16-row frags per wave (2 or 4)
    constexpr int BCH = (BNt * BK) / 2048;  // 4KB staging chunks for B (1 or 2)
    constexpr int LPT = 2 + BCH;            // VMEM instrs per tile per wave

    __shared__ __align__(16) unsigned short As[3][BM * BK];   // 3 x 8 KB
    __shared__ __align__(16) unsigned short Bs[3][BNt * BK];  // 3 x (4|8) KB

    int tid = threadIdx.x;
    int wave = tid >> 6, lane = tid & 63;
    int wr = wave / WC, wc = wave % WC;
    int lrow = lane & 15, quad = lane >> 4;
    int m0 = blockIdx.y * BM, n0 = blockIdx.x * BNt;

    // staging sources: chunk c, thread i stages 16B at LDS ushort (c*2048 + tid*8)
    // -> row (c*256+tid)>>2, col8 (tid&3)*8.
    const unsigned short* ag0 = A + (size_t)(m0 + (tid >> 2)) * K + (tid & 3) * 8;
    const unsigned short* ag1 = A + (size_t)(m0 + 64 + (tid >> 2)) * K + (tid & 3) * 8;
    const unsigned short* bg0 = Bt + (size_t)(n0 + (tid >> 2)) * K + (tid & 3) * 8;
    const unsigned short* bg1 =
        (BCH == 2) ? (Bt + (size_t)(n0 + 64 + (tid >> 2)) * K + (tid & 3) * 8) : nullptr;

    f32x4 acc[MT][4];
#pragma unroll
    for (int i = 0; i < MT; i++)
#pragma unroll
        for (int j = 0; j < 4; j++) acc[i][j] = (f32x4){0.f, 0.f, 0.f, 0.f};

    auto stage = [&](int buf, int koff) {
        GLOAD16(ag0 + koff, &As[buf][wave * 512]);
        GLOAD16(ag1 + koff, &As[buf][2048 + wave * 512]);
        GLOAD16(bg0 + koff, &Bs[buf][wave * 512]);
        if constexpr (BCH == 2) GLOAD16(bg1 + koff, &Bs[buf][2048 + wave * 512]);
    };

    int ntiles = K / BK;  // always >= 4 here
    stage(0, 0);
    stage(1, BK);
    for (int t = 0; t < ntiles; ++t) {
        // tile t landed (allow the LPT loads of tile t+1 to stay in flight);
        // single barrier per tile; "memory" clobber pins LDS reads/stages.
        if (t + 1 < ntiles) {
            asm volatile("s_waitcnt vmcnt(%0)\n\ts_barrier" ::"i"(LPT) : "memory");
        } else {
            asm volatile("s_waitcnt vmcnt(0)\n\ts_barrier" ::: "memory");
        }
        if (t + 2 < ntiles) stage((t + 2) % 3, (t + 2) * BK);
        int cur = t % 3;
        short8 af[MT], bfr[4];
#pragma unroll
        for (int mt = 0; mt < MT; mt++)
            af[mt] = *(const short8*)&As[cur][(wr * (MT * 16) + mt * 16 + lrow) * BK + quad * 8];
#pragma unroll
        for (int nf = 0; nf < 4; nf++)
            bfr[nf] = *(const short8*)&Bs[cur][(wc * 64 + nf * 16 + lrow) * BK + quad * 8];
#pragma unroll
        for (int mt = 0; mt < MT; mt++)
#pragma unroll
            for (int nf = 0; nf < 4; nf++)
                acc[mt][nf] = __builtin_amdgcn_mfma_f32_16x16x32_bf16(af[mt], bfr[nf],
                                                                     acc[mt][nf], 0, 0, 0);
    }

#pragma unroll
    for (int nf = 0; nf < 4; nf++) {
        int gc = n0 + wc * 64 + nf * 16 + lrow;
        float bs = (bias2 && gc >= 128) ? bias2[gc - 128] : (bias ? bias[gc] : 0.f);
        float g = 1.f, bb = 0.f, mm = 0.f, inv = 1.f;
        if (mode == 1) {
            g = bn_g[gc];
            bb = bn_b[gc];
            mm = bn_m[gc];
            inv = rsqrtf(bn_v[gc] + 1e-5f);
        }
        float pg = 0.f, pb = 0.f, pm = 0.f, pinv = 0.f;
        if (mode >= 2 && pn_g) {
            pg = pn_g[gc];
            pb = pn_b[gc];
            pm = pn_m[gc];
            pinv = rsqrtf(pn_v[gc] + 1e-5f);
        }
#pragma unroll
        for (int mt = 0; mt < MT; mt++) {
#pragma unroll
            for (int r = 0; r < 4; r++) {
                int gr = m0 + wr * (MT * 16) + mt * 16 + quad * 4 + r;
                size_t idx = (size_t)gr * N + gc;
                float v = acc[mt][nf][r] + bs;
                if (mode == 0) {
                    CoutB[idx] = f2bf(v);
                } else if (mode == 1) {
                    v = fmaxf(g * (v - mm) * inv + bb, 0.f);
                    CoutB[idx] = f2bf(v);
                } else {
                    if (mode == 2) v += CoutF[idx];
                    CoutF[idx] = v;
                    if (pn_g)
                        Rbuf[idx] = f2bf(fmaxf(pg * (v - pm) * pinv + pb, 0.f));
                }
            }
        }
    }
}

// ---------------- Fused GENConv aggregation ----------------
// One wave per dst node, 2 features per lane (one packed-uint 256B gather per edge).
// Softmax shift-invariance (z = msg*t, msg>0, t~0.1 -> no overflow) lets us skip the
// online-max chain (validated rounds 2-4).  Per-edge math on f32x2 so the compiler
// emits packed VOP3P (v_pk_add/fma/mul/max_f32); exp via raw v_exp_f32 (arg bounded,
// no libm fixup needed).  Edge (src,attr) fused into one int2 load.

template <int XSS>
__global__ __launch_bounds__(256) void agg_kernel(
    const unsigned short* __restrict__ xs,
    const unsigned short* __restrict__ xd, int xds,
    const int2* __restrict__ sedge, const int* __restrict__ off,
    const float* __restrict__ ew, const float* __restrict__ eb,
    const float* __restrict__ tptr, unsigned short* __restrict__ outb) {
    int wave = threadIdx.x >> 6;
    int lane = threadIdx.x & 63;
    int d = blockIdx.x * 4 + wave;  // Nn % 4 == 0, always < Nn
    int s0 = off[d], s1 = off[d + 1];
    int f0 = lane * 2;
    f32x2 wv = *(const f32x2*)(ew + f0);
    f32x2 bv = *(const f32x2*)(eb + f0);
    float c = tptr[0] * 1.44269504088896f;  // fold t and log2(e) into exp2 scale
    const f32x2 zz = {0.f, 0.f};
    const f32x2 ee = {1e-7f, 1e-7f};
    f32x2 den = {0.f, 0.f}, num = {0.f, 0.f};

#define EDGE2(u, av)                                                      \
    {                                                                     \
        f32x2 xv = {bf2f_lo(u), bf2f_hi(u)};                              \
        f32x2 m = __builtin_elementwise_max(xv + bv + (av)*wv, zz) + ee;  \
        f32x2 e;                                                          \
        e.x = __builtin_amdgcn_exp2f(m.x * c);                            \
        e.y = __builtin_amdgcn_exp2f(m.y * c);                            \
        den += e;                                                         \
        num += m * e;                                                     \
    }

    int j = s0;
    for (; j + 3 < s1; j += 4) {
        int2 p0 = sedge[j], p1 = sedge[j + 1], p2 = sedge[j + 2], p3 = sedge[j + 3];
        unsigned int u0 = *(const unsigned int*)(xs + (size_t)p0.x * XSS + f0);
        unsigned int u1 = *(const unsigned int*)(xs + (size_t)p1.x * XSS + f0);
        unsigned int u2 = *(const unsigned int*)(xs + (size_t)p2.x * XSS + f0);
        unsigned int u3 = *(const unsigned int*)(xs + (size_t)p3.x * XSS + f0);
        EDGE2(u0, __int_as_float(p0.y))
        EDGE2(u1, __int_as_float(p1.y))
        EDGE2(u2, __int_as_float(p2.y))
        EDGE2(u3, __int_as_float(p3.y))
    }
    for (; j < s1; j++) {
        int2 p = sedge[j];
        unsigned int u = *(const unsigned int*)(xs + (size_t)p.x * XSS + f0);
        EDGE2(u, __int_as_float(p.y))
    }
#undef EDGE2
    float a0 = (s1 > s0) ? (num.x / fmaxf(den.x, 1e-16f)) : 0.f;
    float a1 = (s1 > s0) ? (num.y / fmaxf(den.y, 1e-16f)) : 0.f;
    unsigned int ud = *(const unsigned int*)(xd + (size_t)d * xds + f0);
    unsigned int lo = f2bf(a0 + bf2f_lo(ud));
    unsigned int hi = f2bf(a1 + bf2f_hi(ud));
    *(unsigned int*)(outb + (size_t)d * Hh + f0) = lo | (hi << 16);
}

// ---------------- final norm + hierarchical mean-pool ----------------

#define PCHUNK 100

__global__ __launch_bounds__(128) void pool_kernel(
    const float* __restrict__ h, const int* __restrict__ batch,
    const float* __restrict__ g, const float* __restrict__ b,
    const float* __restrict__ m, const float* __restrict__ v,
    float* __restrict__ pooled, float* __restrict__ cnt) {
    int hh = threadIdx.x;
    int i0 = blockIdx.x * PCHUNK;
    int i1 = min(i0 + PCHUNK, Nn);
    if (i0 >= Nn) return;
    float gg = g[hh], bb = b[hh], mm = m[hh], inv = rsqrtf(v[hh] + 1e-5f);
    int cur = batch[i0];
    float sum = 0.f, c = 0.f;
    for (int i = i0; i < i1; i++) {
        int gid = batch[i];
        float val = fmaxf(gg * (h[(size_t)i * Hh + hh] - mm) * inv + bb, 0.f);
        if (gid != cur) {
            atomicAdd(&pooled[(size_t)cur * Hh + hh], sum);
            if (hh == 0) atomicAdd(&cnt[cur], c);
            cur = gid;
            sum = 0.f;
            c = 0.f;
        }
        sum += val;
        c += 1.f;
    }
    atomicAdd(&pooled[(size_t)cur * Hh + hh], sum);
    if (hh == 0) atomicAdd(&cnt[cur], c);
}

// ---------------- classifier ----------------

__global__ __launch_bounds__(128) void cls_kernel(const float* __restrict__ pooled,
                                                  const float* __restrict__ cnt,
                                                  const float* __restrict__ clinical,
                                                  const float* __restrict__ w,
                                                  const float* __restrict__ bias,
                                                  float* __restrict__ out) {
    int t = threadIdx.x;
    int g = t >> 1, c = t & 1;
    float inv = 1.f / fmaxf(cnt[g], 1.f);
    float s = bias[c];
    for (int j = 0; j < Hh; j++) s += pooled[g * Hh + j] * inv * w[j * NCc + c];
    for (int k = 0; k < Kk; k++) s += clinical[g * Kk + k] * w[(Hh + k) * NCc + c];
    out[g * NCc + c] = s;
}

// ---------------- launch ----------------

extern "C" void kernel_launch(void* const* d_in, const int* in_sizes, int n_in,
                              void* d_out, int out_size, void* d_ws, size_t ws_size,
                              hipStream_t stream) {
    const float* x = (const float*)d_in[0];
    const int* eidx = (const int*)d_in[1];
    const float* eattr = (const float*)d_in[2];
    const int* batch = (const int*)d_in[3];
    const float* clinical = (const float*)d_in[4];
    const float* lin_src_w = (const float*)d_in[5];
    const float* lin_src_b = (const float*)d_in[6];
    const float* lin_dst_w = (const float*)d_in[7];
    const float* lin_dst_b = (const float*)d_in[8];
    const float* edge_w = (const float*)d_in[9];
    const float* edge_b = (const float*)d_in[10];
    const float* tt = (const float*)d_in[11];
    const float* mlp_w1 = (const float*)d_in[12];
    const float* mlp_b1 = (const float*)d_in[13];
    const float* bn_g = (const float*)d_in[14];
    const float* bn_b = (const float*)d_in[15];
    const float* bn_m = (const float*)d_in[16];
    const float* bn_v = (const float*)d_in[17];
    const float* mlp_w2 = (const float*)d_in[18];
    const float* mlp_b2 = (const float*)d_in[19];
    const float* norm_g = (const float*)d_in[20];
    const float* norm_b = (const float*)d_in[21];
    const float* norm_m = (const float*)d_in[22];
    const float* norm_v = (const float*)d_in[23];
    const float* cls_w = (const float*)d_in[24];
    const float* cls_b = (const float*)d_in[25];
    float* out = (float*)d_out;

    const int* src = eidx;
    const int* dst = eidx + Ee;

    char* ws = (char*)d_ws;
    size_t off_b = 0;
    auto alloc = [&](size_t bytes) -> void* {
        void* p = ws + off_b;
        off_b += (bytes + 255) & ~(size_t)255;
        return p;
    };
    // All GEMM-touched buffers padded to MPAD rows (garbage pad rows never read).
    unsigned short* xsd = (unsigned short*)alloc((size_t)MPAD * 256 * 2);   // proj out
    unsigned short* rbuf = (unsigned short*)alloc((size_t)MPAD * Hh * 2);   // prenorm out
    unsigned short* aggout = (unsigned short*)alloc((size_t)MPAD * Hh * 2);
    unsigned short* hmid = (unsigned short*)alloc((size_t)MPAD * 2 * Hh * 2);
    float* hbuf = (float*)alloc((size_t)MPAD * Hh * 4);
    int* deg = (int*)alloc((Nn + 1) * 4);
    int* offp = (int*)alloc((Nn + 1) * 4);
    int* pos = (int*)alloc((size_t)Nn * 4);
    int* bsum = (int*)alloc(NB * 4);
    int* boff = (int*)alloc(NB * 4);
    int2* sedge = (int2*)alloc((size_t)Ee * 8);
    float* pooled = (float*)alloc((size_t)Gg * Hh * 4);
    float* cntb = (float*)alloc(Gg * 4);
    unsigned short* wt = (unsigned short*)alloc((size_t)327680 * 2);
    // xbf aliases hmid: proj (reads xbf) completes before w1 writes hmid.
    unsigned short* xbf = hmid;

    hipMemsetAsync(deg, 0, (Nn + 1) * 4, stream);
    hipMemsetAsync(pooled, 0, (size_t)Gg * Hh * 4, stream);
    hipMemsetAsync(cntb, 0, Gg * 4, stream);

    hist_kernel<<<(Ee + 255) / 256, 256, 0, stream>>>(dst, deg);
    bsum_kernel<<<NB, 256, 0, stream>>>(deg, bsum);
    bscan_kernel<<<1, 256, 0, stream>>>(bsum, boff, offp);
    offsets_kernel<<<NB, 256, 0, stream>>>(deg, boff, offp, pos);
    scatter_kernel<<<(Ee + 255) / 256, 256, 0, stream>>>(src, dst, eattr, pos, sedge);
    wconv_kernel<<<1280, 256, 0, stream>>>(lin_src_w, lin_dst_w, mlp_w1, mlp_w2, wt);
    xconv_kernel<<<(Nn * Cc / 8 + 255) / 256, 256, 0, stream>>>(x, xbf);

    const unsigned short* wt_proj = wt;
    const unsigned short* wt_w1 = wt + 65536;
    const unsigned short* wt_w2 = wt + 196608;

    // Fused projection: xsd[:, :128] = x@Wsrc+b, xsd[:, 128:] = x@Wdst+b
    dim3 gproj(256 / 128, MPAD / BM);
    gemm_kernel<128><<<gproj, 256, 0, stream>>>(xbf, wt_proj, lin_src_b, lin_dst_b,
                                                nullptr, nullptr, nullptr, nullptr,
                                                nullptr, nullptr, nullptr, nullptr,
                                                nullptr, xsd, nullptr, 256, Cc, 0);

    for (int l = 0; l < Ll; l++) {
        if (l == 0) {
            agg_kernel<256><<<Nn / 4, 256, 0, stream>>>(xsd, xsd + 128, 256, sedge, offp,
                                                        edge_w + l * Hh, edge_b + l * Hh,
                                                        tt + l, aggout);
        } else {
            // rbuf was produced by previous layer's w2 epilogue (fused prenorm)
            agg_kernel<128><<<Nn / 4, 256, 0, stream>>>(rbuf, rbuf, Hh, sedge, offp,
                                                        edge_w + l * Hh, edge_b + l * Hh,
                                                        tt + l, aggout);
        }
        dim3 g1((2 * Hh) / 128, MPAD / BM);
        gemm_kernel<128><<<g1, 256, 0, stream>>>(aggout, wt_w1 + (size_t)l * 32768,
                                                 mlp_b1 + l * 2 * Hh, nullptr,
                                                 bn_g + l * 2 * Hh, bn_b + l * 2 * Hh,
                                                 bn_m + l * 2 * Hh, bn_v + l * 2 * Hh,
                                                 nullptr, nullptr, nullptr, nullptr,
                                                 nullptr, hmid, nullptr, 2 * Hh, Hh, 1);
        // w2 epilogue: residual += (mode 2) / store (mode 3, l==0) into hbuf,
        // plus fused prenorm for next layer into rbuf (norm params l+1).
        const float* png = (l < Ll - 1) ? (norm_g + (l + 1) * Hh) : nullptr;
        const float* pnb = (l < Ll - 1) ? (norm_b + (l + 1) * Hh) : nullptr;
        const float* pnm = (l < Ll - 1) ? (norm_m + (l + 1) * Hh) : nullptr;
        const float* pnv = (l < Ll - 1) ? (norm_v + (l + 1) * Hh) : nullptr;
        dim3 g2(Hh / 64, MPAD / BM);  // BN=64 -> 782 blocks
        gemm_kernel<64><<<g2, 256, 0, stream>>>(hmid, wt_w2 + (size_t)l * 32768,
                                                mlp_b2 + l * Hh, nullptr,
                                                nullptr, nullptr, nullptr, nullptr,
                                                png, pnb, pnm, pnv,
                                                hbuf, nullptr, rbuf, Hh, 2 * Hh,
                                                (l == 0) ? 3 : 2);
    }

    pool_kernel<<<(Nn + PCHUNK - 1) / PCHUNK, 128, 0, stream>>>(hbuf, batch, norm_g, norm_b,
                                                                norm_m, norm_v, pooled, cntb);
    cls_kernel<<<1, 128, 0, stream>>>(pooled, cntb, clinical, cls_w, cls_b, out);
}

// Round 6
// 509.770 us; speedup vs baseline: 1.3291x; 1.1703x over previous
//
#include <hip/hip_runtime.h>
#include <math.h>

// Problem constants (from reference)
#define Nn 50000
#define MPAD 50048  // Nn padded to multiple of 128 (GEMM row tiles, no guards)
#define Ee 500000
#define Cc 256
#define Hh 128
#define Ll 4
#define Gg 64
#define Kk 8
#define NCc 2

#define NB 196  // ceil(Nn/256)

typedef __attribute__((ext_vector_type(8))) short short8;
typedef __attribute__((ext_vector_type(4))) float f32x4;
typedef __attribute__((ext_vector_type(2))) float f32x2;

__device__ __forceinline__ unsigned short f2bf(float f) {
    union { float f; unsigned int u; } v;
    v.f = f;
    unsigned int u = v.u;
    return (unsigned short)((u + 0x7FFFu + ((u >> 16) & 1u)) >> 16);
}
__device__ __forceinline__ float bf2f(unsigned short s) {
    union { float f; unsigned int u; } v;
    v.u = ((unsigned int)s) << 16;
    return v.f;
}
__device__ __forceinline__ float bf2f_lo(unsigned int u) {
    union { float f; unsigned int u; } v;
    v.u = u << 16;
    return v.f;
}
__device__ __forceinline__ float bf2f_hi(unsigned int u) {
    union { float f; unsigned int u; } v;
    v.u = u & 0xffff0000u;
    return v.f;
}

// ---------------- CSR build ----------------

__global__ void hist_kernel(const int* __restrict__ dst, int* __restrict__ deg) {
    int e = blockIdx.x * 256 + threadIdx.x;
    if (e < Ee) atomicAdd(&deg[dst[e]], 1);
}

__global__ __launch_bounds__(256) void bsum_kernel(const int* __restrict__ deg,
                                                   int* __restrict__ bsum) {
    __shared__ int ws[4];
    int t = threadIdx.x;
    int i = blockIdx.x * 256 + t;
    int v = (i < Nn) ? deg[i] : 0;
#pragma unroll
    for (int o = 32; o; o >>= 1) v += __shfl_down(v, o, 64);
    if ((t & 63) == 0) ws[t >> 6] = v;
    __syncthreads();
    if (t == 0) bsum[blockIdx.x] = ws[0] + ws[1] + ws[2] + ws[3];
}

__global__ __launch_bounds__(256) void bscan_kernel(const int* __restrict__ bsum,
                                                    int* __restrict__ boff,
                                                    int* __restrict__ off) {
    __shared__ int sc[256];
    int t = threadIdx.x;
    int v = (t < NB) ? bsum[t] : 0;
    sc[t] = v;
    __syncthreads();
    for (int o = 1; o < 256; o <<= 1) {
        int u = (t >= o) ? sc[t - o] : 0;
        __syncthreads();
        sc[t] += u;
        __syncthreads();
    }
    if (t < NB) boff[t] = sc[t] - v;  // exclusive
    if (t == NB - 1) off[Nn] = sc[t];
}

__global__ __launch_bounds__(256) void offsets_kernel(const int* __restrict__ deg,
                                                      const int* __restrict__ boff,
                                                      int* __restrict__ off,
                                                      int* __restrict__ pos) {
    __shared__ int sc[256];
    int t = threadIdx.x;
    int i = blockIdx.x * 256 + t;
    int v = (i < Nn) ? deg[i] : 0;
    sc[t] = v;
    __syncthreads();
    for (int o = 1; o < 256; o <<= 1) {
        int u = (t >= o) ? sc[t - o] : 0;
        __syncthreads();
        sc[t] += u;
        __syncthreads();
    }
    int excl = sc[t] - v + boff[blockIdx.x];
    if (i < Nn) {
        off[i] = excl;
        pos[i] = excl;
    }
}

__global__ void scatter_kernel(const int* __restrict__ src, const int* __restrict__ dst,
                               const float* __restrict__ attr, int* __restrict__ pos,
                               int2* __restrict__ sedge) {
    int e = blockIdx.x * 256 + threadIdx.x;
    if (e < Ee) {
        int d = dst[e];
        int p = atomicAdd(&pos[d], 1);
        sedge[p] = make_int2(src[e], __float_as_int(attr[e]));
    }
}

// ---------------- weight convert + transpose to bf16 [N][K] ----------------
// wt layout: [0, 65536)            proj  [256 n][256 k]  (n<128: lin_src col, else lin_dst)
//            [65536, 196608)       w1[l] [256 n][128 k]
//            [196608, 327680)      w2[l] [128 n][256 k]

__global__ void wconv_kernel(const float* __restrict__ lin_src_w,
                             const float* __restrict__ lin_dst_w,
                             const float* __restrict__ mlp_w1,
                             const float* __restrict__ mlp_w2,
                             unsigned short* __restrict__ wt) {
    int idx = blockIdx.x * 256 + threadIdx.x;
    if (idx >= 327680) return;
    float val;
    if (idx < 65536) {
        int n = idx >> 8, k = idx & 255;
        val = (n < 128) ? lin_src_w[k * 128 + n] : lin_dst_w[k * 128 + (n - 128)];
    } else if (idx < 196608) {
        int r = idx - 65536;
        int l = r >> 15, e = r & 32767;
        int n = e >> 7, k = e & 127;
        val = mlp_w1[(size_t)l * 32768 + k * 256 + n];
    } else {
        int r = idx - 196608;
        int l = r >> 15, e = r & 32767;
        int n = e >> 8, k = e & 255;
        val = mlp_w2[(size_t)l * 32768 + k * 128 + n];
    }
    wt[idx] = f2bf(val);
}

// ---------------- x fp32 -> bf16 (one-time, vectorized) ----------------

__global__ __launch_bounds__(256) void xconv_kernel(const float* __restrict__ x,
                                                    unsigned short* __restrict__ xbf) {
    int idx = blockIdx.x * 256 + threadIdx.x;  // 8 elems per thread
    if (idx >= (Nn * Cc) / 8) return;
    const float4* p = (const float4*)(x) + (size_t)idx * 2;
    float4 v0 = p[0], v1 = p[1];
    unsigned short t[8];
    t[0] = f2bf(v0.x); t[1] = f2bf(v0.y); t[2] = f2bf(v0.z); t[3] = f2bf(v0.w);
    t[4] = f2bf(v1.x); t[5] = f2bf(v1.y); t[6] = f2bf(v1.z); t[7] = f2bf(v1.w);
    *(short8*)(xbf + (size_t)idx * 8) = *(short8*)t;
}

#define GLOAD16(gp, lp)                                                                       \
    __builtin_amdgcn_global_load_lds(                                                         \
        (const __attribute__((address_space(1))) unsigned int*)(gp),                          \
        (__attribute__((address_space(3))) unsigned int*)(lp), 16, 0, 0)

// ---------------- projection GEMM: xsd = x @ [Wsrc|Wdst] + [bsrc|bdst] ----------------
// 128x128 tile, BK=32, 4 waves, depth-2 prefetch (3 LDS buffers, counted vmcnt).
// Epilogue staged through LDS -> coalesced short8 stores (kills 2.4x write amp).

__global__ __launch_bounds__(256) void proj_kernel(
    const unsigned short* __restrict__ A, const unsigned short* __restrict__ Bt,
    const float* __restrict__ bias, const float* __restrict__ bias2,
    unsigned short* __restrict__ Cout) {
    __shared__ __align__(16) unsigned short SH[24576];  // 48KB: 3xA(8KB) + 3xB(8KB); C reuse
    int tid = threadIdx.x;
    int wave = tid >> 6, lane = tid & 63;
    int wr = wave >> 1, wc = wave & 1;
    int lrow = lane & 15, quad = lane >> 4;
    int m0 = blockIdx.y * 128, n0 = blockIdx.x * 128;
    const int K = 256;

    const unsigned short* ag0 = A + (size_t)(m0 + (tid >> 2)) * K + (tid & 3) * 8;
    const unsigned short* ag1 = A + (size_t)(m0 + 64 + (tid >> 2)) * K + (tid & 3) * 8;
    const unsigned short* bg0 = Bt + (size_t)(n0 + (tid >> 2)) * K + (tid & 3) * 8;
    const unsigned short* bg1 = Bt + (size_t)(n0 + 64 + (tid >> 2)) * K + (tid & 3) * 8;

    f32x4 acc[4][4];
#pragma unroll
    for (int i = 0; i < 4; i++)
#pragma unroll
        for (int j = 0; j < 4; j++) acc[i][j] = (f32x4){0.f, 0.f, 0.f, 0.f};

    auto stage = [&](int buf, int koff) {
        GLOAD16(ag0 + koff, SH + buf * 4096 + wave * 512);
        GLOAD16(ag1 + koff, SH + buf * 4096 + 2048 + wave * 512);
        GLOAD16(bg0 + koff, SH + 12288 + buf * 4096 + wave * 512);
        GLOAD16(bg1 + koff, SH + 12288 + buf * 4096 + 2048 + wave * 512);
    };

    const int ntiles = 8;
    stage(0, 0);
    stage(1, 32);
    for (int t = 0; t < ntiles; ++t) {
        if (t + 1 < ntiles) {
            asm volatile("s_waitcnt vmcnt(4)\n\ts_barrier" ::: "memory");
        } else {
            asm volatile("s_waitcnt vmcnt(0)\n\ts_barrier" ::: "memory");
        }
        if (t + 2 < ntiles) stage((t + 2) % 3, (t + 2) * 32);
        int cur = t % 3;
        const unsigned short* As = SH + cur * 4096;
        const unsigned short* Bs = SH + 12288 + cur * 4096;
        short8 af[4], bfr[4];
#pragma unroll
        for (int mt = 0; mt < 4; mt++)
            af[mt] = *(const short8*)&As[(wr * 64 + mt * 16 + lrow) * 32 + quad * 8];
#pragma unroll
        for (int nf = 0; nf < 4; nf++)
            bfr[nf] = *(const short8*)&Bs[(wc * 64 + nf * 16 + lrow) * 32 + quad * 8];
#pragma unroll
        for (int mt = 0; mt < 4; mt++)
#pragma unroll
            for (int nf = 0; nf < 4; nf++)
                acc[mt][nf] = __builtin_amdgcn_mfma_f32_16x16x32_bf16(af[mt], bfr[nf],
                                                                     acc[mt][nf], 0, 0, 0);
    }

    __syncthreads();  // all frag reads done; reuse SH for C tile
    unsigned short* Cl = SH;  // [128][128] bf16 = 32KB
#pragma unroll
    for (int nf = 0; nf < 4; nf++) {
        int gc = n0 + wc * 64 + nf * 16 + lrow;
        float bs = (gc >= 128) ? bias2[gc - 128] : bias[gc];
        int col = wc * 64 + nf * 16 + lrow;
#pragma unroll
        for (int mt = 0; mt < 4; mt++)
#pragma unroll
            for (int r = 0; r < 4; r++)
                Cl[(wr * 64 + mt * 16 + quad * 4 + r) * 128 + col] = f2bf(acc[mt][nf][r] + bs);
    }
    __syncthreads();
#pragma unroll
    for (int p = 0; p < 8; p++) {
        int vid = p * 256 + tid;
        int row = vid >> 4, cg = (vid & 15) * 8;
        short8 v = *(const short8*)&Cl[row * 128 + cg];
        *(short8*)(Cout + (size_t)(m0 + row) * 256 + n0 + cg) = v;
    }
}

// ---------------- fused per-layer MLP: hbuf (+)= agg @ W1 -> BN -> ReLU -> @ W2 + b2,
//                  plus next-layer prenorm rbuf = bf16(relu(BN_pn(hbuf))) ----------------
// Per 64-node tile: phase 1 writes hmid to LDS only (never HBM); phase 2 consumes it.
// 256 threads / 4 waves.  LDS: 40KB staging (+C2 reuse) + 33KB hmid -> 2 blocks/CU.

__global__ __launch_bounds__(256) void mlp_kernel(
    const unsigned short* __restrict__ A,    // aggout [MPAD][128] bf16
    const unsigned short* __restrict__ W1,   // [256 n][128 k] bf16
    const unsigned short* __restrict__ W2,   // [128 n][256 k] bf16
    const float* __restrict__ b1, const float* __restrict__ bn_g,
    const float* __restrict__ bn_b, const float* __restrict__ bn_m,
    const float* __restrict__ bn_v, const float* __restrict__ b2,
    const float* __restrict__ pn_g, const float* __restrict__ pn_b,
    const float* __restrict__ pn_m, const float* __restrict__ pn_v,
    float* __restrict__ hbuf, unsigned short* __restrict__ rbuf, int rmw) {
    __shared__ __align__(16) unsigned short S[20480];    // 40KB: A1 dbuf 2x4KB @0, B1 dbuf 2x16KB @8KB
    __shared__ __align__(16) unsigned short Hm[64 * 264];  // hmid, padded rows (16B-aligned)

    int tid = threadIdx.x;
    int wave = tid >> 6, lane = tid & 63;
    int lrow = lane & 15, quad = lane >> 4;
    int m0 = blockIdx.x * 64;

    // ---- phase 1: Hm = relu(BN(A[m0:m0+64] @ W1 + b1))  (64x256) ----
    const unsigned short* ag = A + (size_t)(m0 + (tid >> 2)) * 128 + (tid & 3) * 8;
    const unsigned short* bg = W1 + (size_t)(tid >> 2) * 128 + (tid & 3) * 8;

    f32x4 acc1[4][4];
#pragma unroll
    for (int i = 0; i < 4; i++)
#pragma unroll
        for (int j = 0; j < 4; j++) acc1[i][j] = (f32x4){0.f, 0.f, 0.f, 0.f};

    auto stage1 = [&](int buf, int k0) {
        GLOAD16(ag + k0, S + buf * 2048 + wave * 512);
#pragma unroll
        for (int c = 0; c < 4; c++)
            GLOAD16(bg + (size_t)c * 64 * 128 + k0,
                    S + 4096 + buf * 8192 + c * 2048 + wave * 512);
    };

    stage1(0, 0);
    __syncthreads();
    for (int t = 0; t < 4; ++t) {
        if (t + 1 < 4) stage1((t + 1) & 1, (t + 1) * 32);
        int cur = t & 1;
        const unsigned short* A1s = S + cur * 2048;
        const unsigned short* B1s = S + 4096 + cur * 8192;
        short8 af[4], bfr[4];
#pragma unroll
        for (int mt = 0; mt < 4; mt++)
            af[mt] = *(const short8*)&A1s[(mt * 16 + lrow) * 32 + quad * 8];
#pragma unroll
        for (int nf = 0; nf < 4; nf++)
            bfr[nf] = *(const short8*)&B1s[(wave * 64 + nf * 16 + lrow) * 32 + quad * 8];
#pragma unroll
        for (int mt = 0; mt < 4; mt++)
#pragma unroll
            for (int nf = 0; nf < 4; nf++)
                acc1[mt][nf] = __builtin_amdgcn_mfma_f32_16x16x32_bf16(af[mt], bfr[nf],
                                                                      acc1[mt][nf], 0, 0, 0);
        __syncthreads();
    }

    // epilogue 1 -> Hm (LDS only)
#pragma unroll
    for (int nf = 0; nf < 4; nf++) {
        int gc = wave * 64 + nf * 16 + lrow;
        float bs = b1[gc];
        float g = bn_g[gc], bb = bn_b[gc], mm = bn_m[gc];
        float inv = rsqrtf(bn_v[gc] + 1e-5f);
#pragma unroll
        for (int mt = 0; mt < 4; mt++)
#pragma unroll
            for (int r = 0; r < 4; r++) {
                float v = acc1[mt][nf][r] + bs;
                v = fmaxf(g * (v - mm) * inv + bb, 0.f);
                Hm[(mt * 16 + quad * 4 + r) * 264 + gc] = f2bf(v);
            }
    }
    __syncthreads();  // Hm complete; phase-1 staging region free

    // ---- phase 2: C2 = Hm @ W2 + b2  (64x128) ----
    const unsigned short* b2g0 = W2 + (size_t)(tid >> 2) * 256 + (tid & 3) * 8;
    const unsigned short* b2g1 = W2 + (size_t)(64 + (tid >> 2)) * 256 + (tid & 3) * 8;

    f32x4 acc2[4][2];
#pragma unroll
    for (int i = 0; i < 4; i++)
#pragma unroll
        for (int j = 0; j < 2; j++) acc2[i][j] = (f32x4){0.f, 0.f, 0.f, 0.f};

    auto stage2 = [&](int buf, int k0) {
        GLOAD16(b2g0 + k0, S + buf * 4096 + wave * 512);
        GLOAD16(b2g1 + k0, S + buf * 4096 + 2048 + wave * 512);
    };

    stage2(0, 0);
    __syncthreads();
    for (int t = 0; t < 8; ++t) {
        if (t + 1 < 8) stage2((t + 1) & 1, (t + 1) * 32);
        int cur = t & 1;
        const unsigned short* B2s = S + cur * 4096;
        short8 af[4], bfr[2];
#pragma unroll
        for (int mt = 0; mt < 4; mt++)
            af[mt] = *(const short8*)&Hm[(mt * 16 + lrow) * 264 + t * 32 + quad * 8];
#pragma unroll
        for (int nf = 0; nf < 2; nf++)
            bfr[nf] = *(const short8*)&B2s[(wave * 32 + nf * 16 + lrow) * 32 + quad * 8];
#pragma unroll
        for (int mt = 0; mt < 4; mt++)
#pragma unroll
            for (int nf = 0; nf < 2; nf++)
                acc2[mt][nf] = __builtin_amdgcn_mfma_f32_16x16x32_bf16(af[mt], bfr[nf],
                                                                      acc2[mt][nf], 0, 0, 0);
        __syncthreads();
    }

    // epilogue 2: stage fp32 C2 in LDS (over staging region), then coalesced writeback
    float* C2 = (float*)S;  // [64][128] fp32 = 32KB
#pragma unroll
    for (int nf = 0; nf < 2; nf++) {
        int gc = wave * 32 + nf * 16 + lrow;
        float bs = b2[gc];
#pragma unroll
        for (int mt = 0; mt < 4; mt++)
#pragma unroll
            for (int r = 0; r < 4; r++)
                C2[(mt * 16 + quad * 4 + r) * 128 + gc] = acc2[mt][nf][r] + bs;
    }
    __syncthreads();
#pragma unroll
    for (int p = 0; p < 8; p++) {
        int vid = p * 256 + tid;
        int row = vid >> 5, c4 = (vid & 31) * 4;
        f32x4 v = *(const f32x4*)&C2[row * 128 + c4];
        float* hp = hbuf + (size_t)(m0 + row) * 128 + c4;
        if (rmw) v += *(const f32x4*)hp;
        *(f32x4*)hp = v;
        if (pn_g) {
            f32x4 pg = *(const f32x4*)&pn_g[c4];
            f32x4 pb = *(const f32x4*)&pn_b[c4];
            f32x4 pm = *(const f32x4*)&pn_m[c4];
            f32x4 pv = *(const f32x4*)&pn_v[c4];
            unsigned int w0, w1;
            float r0 = fmaxf(pg[0] * (v[0] - pm[0]) * rsqrtf(pv[0] + 1e-5f) + pb[0], 0.f);
            float r1 = fmaxf(pg[1] * (v[1] - pm[1]) * rsqrtf(pv[1] + 1e-5f) + pb[1], 0.f);
            float r2 = fmaxf(pg[2] * (v[2] - pm[2]) * rsqrtf(pv[2] + 1e-5f) + pb[2], 0.f);
            float r3 = fmaxf(pg[3] * (v[3] - pm[3]) * rsqrtf(pv[3] + 1e-5f) + pb[3], 0.f);
            w0 = (unsigned int)f2bf(r0) | ((unsigned int)f2bf(r1) << 16);
            w1 = (unsigned int)f2bf(r2) | ((unsigned int)f2bf(r3) << 16);
            uint2 pk = make_uint2(w0, w1);
            *(uint2*)(rbuf + (size_t)(m0 + row) * 128 + c4) = pk;
        }
    }
}

// ---------------- Fused GENConv aggregation ----------------
// One wave per dst node, 2 features per lane (one packed-uint 256B gather per edge).
// Softmax shift-invariance (z = msg*t, msg>0, t~0.1 -> no overflow) lets us skip the
// online-max chain (validated rounds 2-5).  Packed f32x2 math + raw v_exp_f32.

template <int XSS>
__global__ __launch_bounds__(256) void agg_kernel(
    const unsigned short* __restrict__ xs,
    const unsigned short* __restrict__ xd, int xds,
    const int2* __restrict__ sedge, const int* __restrict__ off,
    const float* __restrict__ ew, const float* __restrict__ eb,
    const float* __restrict__ tptr, unsigned short* __restrict__ outb) {
    int wave = threadIdx.x >> 6;
    int lane = threadIdx.x & 63;
    int d = blockIdx.x * 4 + wave;  // Nn % 4 == 0, always < Nn
    int s0 = off[d], s1 = off[d + 1];
    int f0 = lane * 2;
    f32x2 wv = *(const f32x2*)(ew + f0);
    f32x2 bv = *(const f32x2*)(eb + f0);
    float c = tptr[0] * 1.44269504088896f;  // fold t and log2(e) into exp2 scale
    const f32x2 zz = {0.f, 0.f};
    const f32x2 ee = {1e-7f, 1e-7f};
    f32x2 den = {0.f, 0.f}, num = {0.f, 0.f};

#define EDGE2(u, av)                                                      \
    {                                                                     \
        f32x2 xv = {bf2f_lo(u), bf2f_hi(u)};                              \
        f32x2 m = __builtin_elementwise_max(xv + bv + (av)*wv, zz) + ee;  \
        f32x2 e;                                                          \
        e.x = __builtin_amdgcn_exp2f(m.x * c);                            \
        e.y = __builtin_amdgcn_exp2f(m.y * c);                            \
        den += e;                                                         \
        num += m * e;                                                     \
    }

    int j = s0;
    for (; j + 3 < s1; j += 4) {
        int2 p0 = sedge[j], p1 = sedge[j + 1], p2 = sedge[j + 2], p3 = sedge[j + 3];
        unsigned int u0 = *(const unsigned int*)(xs + (size_t)p0.x * XSS + f0);
        unsigned int u1 = *(const unsigned int*)(xs + (size_t)p1.x * XSS + f0);
        unsigned int u2 = *(const unsigned int*)(xs + (size_t)p2.x * XSS + f0);
        unsigned int u3 = *(const unsigned int*)(xs + (size_t)p3.x * XSS + f0);
        EDGE2(u0, __int_as_float(p0.y))
        EDGE2(u1, __int_as_float(p1.y))
        EDGE2(u2, __int_as_float(p2.y))
        EDGE2(u3, __int_as_float(p3.y))
    }
    for (; j < s1; j++) {
        int2 p = sedge[j];
        unsigned int u = *(const unsigned int*)(xs + (size_t)p.x * XSS + f0);
        EDGE2(u, __int_as_float(p.y))
    }
#undef EDGE2
    float a0 = (s1 > s0) ? (num.x / fmaxf(den.x, 1e-16f)) : 0.f;
    float a1 = (s1 > s0) ? (num.y / fmaxf(den.y, 1e-16f)) : 0.f;
    unsigned int ud = *(const unsigned int*)(xd + (size_t)d * xds + f0);
    unsigned int lo = f2bf(a0 + bf2f_lo(ud));
    unsigned int hi = f2bf(a1 + bf2f_hi(ud));
    *(unsigned int*)(outb + (size_t)d * Hh + f0) = lo | (hi << 16);
}

// ---------------- final norm + hierarchical mean-pool ----------------

#define PCHUNK 100

__global__ __launch_bounds__(128) void pool_kernel(
    const float* __restrict__ h, const int* __restrict__ batch,
    const float* __restrict__ g, const float* __restrict__ b,
    const float* __restrict__ m, const float* __restrict__ v,
    float* __restrict__ pooled, float* __restrict__ cnt) {
    int hh = threadIdx.x;
    int i0 = blockIdx.x * PCHUNK;
    int i1 = min(i0 + PCHUNK, Nn);
    if (i0 >= Nn) return;
    float gg = g[hh], bb = b[hh], mm = m[hh], inv = rsqrtf(v[hh] + 1e-5f);
    int cur = batch[i0];
    float sum = 0.f, c = 0.f;
    for (int i = i0; i < i1; i++) {
        int gid = batch[i];
        float val = fmaxf(gg * (h[(size_t)i * Hh + hh] - mm) * inv + bb, 0.f);
        if (gid != cur) {
            atomicAdd(&pooled[(size_t)cur * Hh + hh], sum);
            if (hh == 0) atomicAdd(&cnt[cur], c);
            cur = gid;
            sum = 0.f;
            c = 0.f;
        }
        sum += val;
        c += 1.f;
    }
    atomicAdd(&pooled[(size_t)cur * Hh + hh], sum);
    if (hh == 0) atomicAdd(&cnt[cur], c);
}

// ---------------- classifier ----------------

__global__ __launch_bounds__(128) void cls_kernel(const float* __restrict__ pooled,
                                                  const float* __restrict__ cnt,
                                                  const float* __restrict__ clinical,
                                                  const float* __restrict__ w,
                                                  const float* __restrict__ bias,
                                                  float* __restrict__ out) {
    int t = threadIdx.x;
    int g = t >> 1, c = t & 1;
    float inv = 1.f / fmaxf(cnt[g], 1.f);
    float s = bias[c];
    for (int j = 0; j < Hh; j++) s += pooled[g * Hh + j] * inv * w[j * NCc + c];
    for (int k = 0; k < Kk; k++) s += clinical[g * Kk + k] * w[(Hh + k) * NCc + c];
    out[g * NCc + c] = s;
}

// ---------------- launch ----------------

extern "C" void kernel_launch(void* const* d_in, const int* in_sizes, int n_in,
                              void* d_out, int out_size, void* d_ws, size_t ws_size,
                              hipStream_t stream) {
    const float* x = (const float*)d_in[0];
    const int* eidx = (const int*)d_in[1];
    const float* eattr = (const float*)d_in[2];
    const int* batch = (const int*)d_in[3];
    const float* clinical = (const float*)d_in[4];
    const float* lin_src_w = (const float*)d_in[5];
    const float* lin_src_b = (const float*)d_in[6];
    const float* lin_dst_w = (const float*)d_in[7];
    const float* lin_dst_b = (const float*)d_in[8];
    const float* edge_w = (const float*)d_in[9];
    const float* edge_b = (const float*)d_in[10];
    const float* tt = (const float*)d_in[11];
    const float* mlp_w1 = (const float*)d_in[12];
    const float* mlp_b1 = (const float*)d_in[13];
    const float* bn_g = (const float*)d_in[14];
    const float* bn_b = (const float*)d_in[15];
    const float* bn_m = (const float*)d_in[16];
    const float* bn_v = (const float*)d_in[17];
    const float* mlp_w2 = (const float*)d_in[18];
    const float* mlp_b2 = (const float*)d_in[19];
    const float* norm_g = (const float*)d_in[20];
    const float* norm_b = (const float*)d_in[21];
    const float* norm_m = (const float*)d_in[22];
    const float* norm_v = (const float*)d_in[23];
    const float* cls_w = (const float*)d_in[24];
    const float* cls_b = (const float*)d_in[25];
    float* out = (float*)d_out;

    const int* src = eidx;
    const int* dst = eidx + Ee;

    char* ws = (char*)d_ws;
    size_t off_b = 0;
    auto alloc = [&](size_t bytes) -> void* {
        void* p = ws + off_b;
        off_b += (bytes + 255) & ~(size_t)255;
        return p;
    };
    // All GEMM-touched buffers padded to MPAD rows (garbage pad rows never read).
    unsigned short* xsd = (unsigned short*)alloc((size_t)MPAD * 256 * 2);   // proj out
    unsigned short* rbuf = (unsigned short*)alloc((size_t)MPAD * Hh * 2);   // prenorm out
    unsigned short* aggout = (unsigned short*)alloc((size_t)MPAD * Hh * 2);
    unsigned short* xbf = (unsigned short*)alloc((size_t)MPAD * 256 * 2);
    float* hbuf = (float*)alloc((size_t)MPAD * Hh * 4);
    int* deg = (int*)alloc((Nn + 1) * 4);
    int* offp = (int*)alloc((Nn + 1) * 4);
    int* pos = (int*)alloc((size_t)Nn * 4);
    int* bsum = (int*)alloc(NB * 4);
    int* boff = (int*)alloc(NB * 4);
    int2* sedge = (int2*)alloc((size_t)Ee * 8);
    float* pooled = (float*)alloc((size_t)Gg * Hh * 4);
    float* cntb = (float*)alloc(Gg * 4);
    unsigned short* wt = (unsigned short*)alloc((size_t)327680 * 2);

    hipMemsetAsync(deg, 0, (Nn + 1) * 4, stream);
    hipMemsetAsync(pooled, 0, (size_t)Gg * Hh * 4, stream);
    hipMemsetAsync(cntb, 0, Gg * 4, stream);

    hist_kernel<<<(Ee + 255) / 256, 256, 0, stream>>>(dst, deg);
    bsum_kernel<<<NB, 256, 0, stream>>>(deg, bsum);
    bscan_kernel<<<1, 256, 0, stream>>>(bsum, boff, offp);
    offsets_kernel<<<NB, 256, 0, stream>>>(deg, boff, offp, pos);
    scatter_kernel<<<(Ee + 255) / 256, 256, 0, stream>>>(src, dst, eattr, pos, sedge);
    wconv_kernel<<<1280, 256, 0, stream>>>(lin_src_w, lin_dst_w, mlp_w1, mlp_w2, wt);
    xconv_kernel<<<(Nn * Cc / 8 + 255) / 256, 256, 0, stream>>>(x, xbf);

    const unsigned short* wt_proj = wt;
    const unsigned short* wt_w1 = wt + 65536;
    const unsigned short* wt_w2 = wt + 196608;

    // Fused projection: xsd[:, :128] = x@Wsrc+b, xsd[:, 128:] = x@Wdst+b
    dim3 gproj(2, MPAD / 128);
    proj_kernel<<<gproj, 256, 0, stream>>>(xbf, wt_proj, lin_src_b, lin_dst_b, xsd);

    for (int l = 0; l < Ll; l++) {
        if (l == 0) {
            agg_kernel<256><<<Nn / 4, 256, 0, stream>>>(xsd, xsd + 128, 256, sedge, offp,
                                                        edge_w + l * Hh, edge_b + l * Hh,
                                                        tt + l, aggout);
        } else {
            agg_kernel<128><<<Nn / 4, 256, 0, stream>>>(rbuf, rbuf, Hh, sedge, offp,
                                                        edge_w + l * Hh, edge_b + l * Hh,
                                                        tt + l, aggout);
        }
        const float* png = (l < Ll - 1) ? (norm_g + (l + 1) * Hh) : nullptr;
        const float* pnb = (l < Ll - 1) ? (norm_b + (l + 1) * Hh) : nullptr;
        const float* pnm = (l < Ll - 1) ? (norm_m + (l + 1) * Hh) : nullptr;
        const float* pnv = (l < Ll - 1) ? (norm_v + (l + 1) * Hh) : nullptr;
        mlp_kernel<<<MPAD / 64, 256, 0, stream>>>(
            aggout, wt_w1 + (size_t)l * 32768, wt_w2 + (size_t)l * 32768,
            mlp_b1 + l * 2 * Hh, bn_g + l * 2 * Hh, bn_b + l * 2 * Hh,
            bn_m + l * 2 * Hh, bn_v + l * 2 * Hh, mlp_b2 + l * Hh,
            png, pnb, pnm, pnv, hbuf, rbuf, (l == 0) ? 0 : 1);
    }

    pool_kernel<<<(Nn + PCHUNK - 1) / PCHUNK, 128, 0, stream>>>(hbuf, batch, norm_g, norm_b,
                                                                norm_m, norm_v, pooled, cntb);
    cls_kernel<<<1, 128, 0, stream>>>(pooled, cntb, clinical, cls_w, cls_b, out);
}